// Round 1
// baseline (655.544 us; speedup 1.0000x reference)
//
#include <hip/hip_runtime.h>

#define ATTN_SCALE 0.17677669529663687f  // 32^-0.5

// ---------------------------------------------------------------------------
// Kernel 1: fused 1x1 projections  q = Wq@x, qb = Wqb@x, kvb = Wkvb@x
// Output layout TRANSPOSED: y[b][p][oc]
// GEMM per batch: C[oc][p] = W[oc][c] * x[c][p], oc in [0,1024)
// ---------------------------------------------------------------------------
__global__ __launch_bounds__(256) void proj_kernel(
    const float* __restrict__ x, const float* __restrict__ Wq,
    const float* __restrict__ Wqb, const float* __restrict__ Wkvb,
    float* __restrict__ qT, float* __restrict__ qbT, float* __restrict__ kvbT)
{
    __shared__ float As[64][68];  // As[kk][m] = W[oc0+m][k0+kk]
    __shared__ float Bs[64][68];  // Bs[kk][n] = x[b][k0+kk][p0+n]
    const int tid = threadIdx.x;
    const int tx = tid & 15, ty = tid >> 4;
    const int p0  = blockIdx.x * 64;
    const int oc0 = blockIdx.y * 64;
    const int b   = blockIdx.z;

    const float* W; float* dst; int dstLd, dstOc;
    if (oc0 < 256)      { W = Wq   + (size_t)oc0 * 256;        dst = qT   + (size_t)b * 4096 * 256; dstLd = 256; dstOc = oc0; }
    else if (oc0 < 512) { W = Wqb  + (size_t)(oc0 - 256) * 256; dst = qbT  + (size_t)b * 4096 * 256; dstLd = 256; dstOc = oc0 - 256; }
    else                { W = Wkvb + (size_t)(oc0 - 512) * 256; dst = kvbT + (size_t)b * 4096 * 512; dstLd = 512; dstOc = oc0 - 512; }

    const float* xb = x + (size_t)b * 256 * 4096 + p0;

    float acc[4][4] = {};
    for (int k0 = 0; k0 < 256; k0 += 64) {
        {   // stage A (transpose W rows into K-major)
            const int m  = tid >> 4;
            const int kk = (tid & 15) * 4;
            #pragma unroll
            for (int l = 0; l < 4; ++l) {
                const int mm = m + l * 16;
                const float4 w4 = *(const float4*)&W[(size_t)mm * 256 + k0 + kk];
                As[kk + 0][mm] = w4.x; As[kk + 1][mm] = w4.y;
                As[kk + 2][mm] = w4.z; As[kk + 3][mm] = w4.w;
            }
        }
        {   // stage B (source already K-major rows; contiguous along p)
            const int kk = tid >> 2;
            const int n  = (tid & 3) * 16;
            const float* src = xb + (size_t)(k0 + kk) * 4096 + n;
            float4* d4 = (float4*)&Bs[kk][n];
            d4[0] = ((const float4*)src)[0];
            d4[1] = ((const float4*)src)[1];
            d4[2] = ((const float4*)src)[2];
            d4[3] = ((const float4*)src)[3];
        }
        __syncthreads();
        #pragma unroll 8
        for (int kk = 0; kk < 64; ++kk) {
            const float4 a  = *(const float4*)&As[kk][ty * 4];
            const float4 bv = *(const float4*)&Bs[kk][tx * 4];
            acc[0][0] += a.x * bv.x; acc[0][1] += a.x * bv.y; acc[0][2] += a.x * bv.z; acc[0][3] += a.x * bv.w;
            acc[1][0] += a.y * bv.x; acc[1][1] += a.y * bv.y; acc[1][2] += a.y * bv.z; acc[1][3] += a.y * bv.w;
            acc[2][0] += a.z * bv.x; acc[2][1] += a.z * bv.y; acc[2][2] += a.z * bv.z; acc[2][3] += a.z * bv.w;
            acc[3][0] += a.w * bv.x; acc[3][1] += a.w * bv.y; acc[3][2] += a.w * bv.z; acc[3][3] += a.w * bv.w;
        }
        __syncthreads();
    }
    #pragma unroll
    for (int pj = 0; pj < 4; ++pj) {
        const float4 v = make_float4(acc[0][pj], acc[1][pj], acc[2][pj], acc[3][pj]);
        *(float4*)&dst[(size_t)(p0 + tx * 4 + pj) * dstLd + dstOc + ty * 4] = v;
    }
}

// ---------------------------------------------------------------------------
// Kernel 2: 2x2 stride-2 VALID conv (kv) as GEMM with gathered B.
// K = c*4 + di*2 + dj (matches Wkv flat layout).  Output kT/vT[b][pp][c].
// ---------------------------------------------------------------------------
__global__ __launch_bounds__(256) void convkv_kernel(
    const float* __restrict__ x, const float* __restrict__ Wkv,
    float* __restrict__ kT, float* __restrict__ vT)
{
    __shared__ float As[64][68];
    __shared__ float Bs[64][68];
    const int tid = threadIdx.x;
    const int tx = tid & 15, ty = tid >> 4;
    const int pp0 = blockIdx.x * 64;
    const int oc0 = blockIdx.y * 64;
    const int b   = blockIdx.z;

    const float* W  = Wkv + (size_t)oc0 * 1024;
    const float* xb = x + (size_t)b * 256 * 4096;

    float acc[4][4] = {};
    for (int k0 = 0; k0 < 1024; k0 += 64) {
        {   // stage A
            const int m  = tid >> 4;
            const int kk = (tid & 15) * 4;
            #pragma unroll
            for (int l = 0; l < 4; ++l) {
                const int mm = m + l * 16;
                const float4 w4 = *(const float4*)&W[(size_t)mm * 1024 + k0 + kk];
                As[kk + 0][mm] = w4.x; As[kk + 1][mm] = w4.y;
                As[kk + 2][mm] = w4.z; As[kk + 3][mm] = w4.w;
            }
        }
        // stage B: gather 2x2-patch elements
        #pragma unroll
        for (int l = 0; l < 16; ++l) {
            const int e  = l * 256 + tid;
            const int kk = e >> 6, n = e & 63;
            const int kg = k0 + kk;
            const int c = kg >> 2, di = (kg >> 1) & 1, dj = kg & 1;
            const int pp = pp0 + n;
            const int i = pp >> 5, j = pp & 31;
            Bs[kk][n] = xb[(size_t)c * 4096 + (2 * i + di) * 64 + 2 * j + dj];
        }
        __syncthreads();
        #pragma unroll 8
        for (int kk = 0; kk < 64; ++kk) {
            const float4 a  = *(const float4*)&As[kk][ty * 4];
            const float4 bv = *(const float4*)&Bs[kk][tx * 4];
            acc[0][0] += a.x * bv.x; acc[0][1] += a.x * bv.y; acc[0][2] += a.x * bv.z; acc[0][3] += a.x * bv.w;
            acc[1][0] += a.y * bv.x; acc[1][1] += a.y * bv.y; acc[1][2] += a.y * bv.z; acc[1][3] += a.y * bv.w;
            acc[2][0] += a.z * bv.x; acc[2][1] += a.z * bv.y; acc[2][2] += a.z * bv.z; acc[2][3] += a.z * bv.w;
            acc[3][0] += a.w * bv.x; acc[3][1] += a.w * bv.y; acc[3][2] += a.w * bv.z; acc[3][3] += a.w * bv.w;
        }
        __syncthreads();
    }
    float* dst; int o;
    if (oc0 < 256) { dst = kT + (size_t)b * 1024 * 256; o = oc0; }
    else           { dst = vT + (size_t)b * 1024 * 256; o = oc0 - 256; }
    #pragma unroll
    for (int pj = 0; pj < 4; ++pj) {
        const float4 v = make_float4(acc[0][pj], acc[1][pj], acc[2][pj], acc[3][pj]);
        *(float4*)&dst[(size_t)(pp0 + tx * 4 + pj) * 256 + o + ty * 4] = v;
    }
}

// ---------------------------------------------------------------------------
// Kernel 3: spatial-reduction attention (flash-style, online softmax).
// One q-row per thread. Reads qT rows, writes result IN PLACE over qT
// (each thread consumes its row into registers before writing).
// ---------------------------------------------------------------------------
__global__ __launch_bounds__(256) void attn_img_kernel(
    const float* __restrict__ kT, const float* __restrict__ vT,
    float* __restrict__ qT)
{
    __shared__ float Ks[64][32];
    __shared__ float Vs[64][32];
    const int tid = threadIdx.x;
    const int bh = blockIdx.y;
    const int b = bh >> 3, h = bh & 7;
    const int p = blockIdx.x * 256 + tid;

    float* qrow = qT + ((size_t)b * 4096 + p) * 256 + h * 32;
    float q[32];
    #pragma unroll
    for (int i = 0; i < 8; ++i) {
        const float4 t = ((const float4*)qrow)[i];
        q[4 * i + 0] = t.x * ATTN_SCALE; q[4 * i + 1] = t.y * ATTN_SCALE;
        q[4 * i + 2] = t.z * ATTN_SCALE; q[4 * i + 3] = t.w * ATTN_SCALE;
    }

    float acc[32] = {};
    float m = -3.0e38f, l = 0.f;
    const float* kb = kT + (size_t)b * 1024 * 256 + h * 32;
    const float* vb = vT + (size_t)b * 1024 * 256 + h * 32;

    for (int t0 = 0; t0 < 1024; t0 += 64) {
        __syncthreads();
        {   // stage 64 k-rows and v-rows (32 floats each)
            const int row = tid >> 2;
            const int cc  = (tid & 3) * 8;
            *(float4*)&Ks[row][cc]     = *(const float4*)&kb[(size_t)(t0 + row) * 256 + cc];
            *(float4*)&Ks[row][cc + 4] = *(const float4*)&kb[(size_t)(t0 + row) * 256 + cc + 4];
            *(float4*)&Vs[row][cc]     = *(const float4*)&vb[(size_t)(t0 + row) * 256 + cc];
            *(float4*)&Vs[row][cc + 4] = *(const float4*)&vb[(size_t)(t0 + row) * 256 + cc + 4];
        }
        __syncthreads();
        for (int pp = 0; pp < 64; ++pp) {
            float s = 0.f;
            #pragma unroll
            for (int cc = 0; cc < 32; ++cc) s += q[cc] * Ks[pp][cc];
            if (s <= m) {
                const float pe = __expf(s - m);
                l += pe;
                #pragma unroll
                for (int cc = 0; cc < 32; ++cc) acc[cc] += pe * Vs[pp][cc];
            } else {
                const float sc = __expf(m - s);
                l = l * sc + 1.f;
                #pragma unroll
                for (int cc = 0; cc < 32; ++cc) acc[cc] = acc[cc] * sc + Vs[pp][cc];
                m = s;
            }
        }
    }
    const float r = 1.f / l;
    #pragma unroll
    for (int i = 0; i < 8; ++i) {
        const float4 o = make_float4(acc[4 * i] * r, acc[4 * i + 1] * r,
                                     acc[4 * i + 2] * r, acc[4 * i + 3] * r);
        ((float4*)qrow)[i] = o;
    }
}

// ---------------------------------------------------------------------------
// Kernel 4: batch-axis attention (4x4 per (pixel,head)); adds into sum buffer.
// ---------------------------------------------------------------------------
__global__ __launch_bounds__(256) void attn_batch_kernel(
    const float* __restrict__ qbT, const float* __restrict__ kvbT,
    float* __restrict__ sumT)
{
    const int tid = threadIdx.x;
    const int b1 = tid & 3, h = (tid >> 2) & 7, pl = tid >> 5;
    const int p = blockIdx.x * 8 + pl;

    const float* qrow = qbT + ((size_t)b1 * 4096 + p) * 256 + h * 32;
    float q[32];
    #pragma unroll
    for (int i = 0; i < 8; ++i) {
        const float4 t = ((const float4*)qrow)[i];
        q[4 * i + 0] = t.x * ATTN_SCALE; q[4 * i + 1] = t.y * ATTN_SCALE;
        q[4 * i + 2] = t.z * ATTN_SCALE; q[4 * i + 3] = t.w * ATTN_SCALE;
    }

    float s[4];
    #pragma unroll
    for (int b2 = 0; b2 < 4; ++b2) {
        const float4* k4 = (const float4*)(kvbT + ((size_t)b2 * 4096 + p) * 512 + h * 32);
        float d = 0.f;
        #pragma unroll
        for (int i = 0; i < 8; ++i) {
            const float4 kv = k4[i];
            d += q[4 * i] * kv.x + q[4 * i + 1] * kv.y + q[4 * i + 2] * kv.z + q[4 * i + 3] * kv.w;
        }
        s[b2] = d;
    }
    const float mx = fmaxf(fmaxf(s[0], s[1]), fmaxf(s[2], s[3]));
    float w[4];
    float lsum = 0.f;
    #pragma unroll
    for (int b2 = 0; b2 < 4; ++b2) { w[b2] = __expf(s[b2] - mx); lsum += w[b2]; }
    const float inv = 1.f / lsum;
    #pragma unroll
    for (int b2 = 0; b2 < 4; ++b2) w[b2] *= inv;

    float acc[32] = {};
    #pragma unroll
    for (int b2 = 0; b2 < 4; ++b2) {
        const float4* v4 = (const float4*)(kvbT + ((size_t)b2 * 4096 + p) * 512 + 256 + h * 32);
        #pragma unroll
        for (int i = 0; i < 8; ++i) {
            const float4 vv = v4[i];
            acc[4 * i + 0] += w[b2] * vv.x; acc[4 * i + 1] += w[b2] * vv.y;
            acc[4 * i + 2] += w[b2] * vv.z; acc[4 * i + 3] += w[b2] * vv.w;
        }
    }
    float4* o4 = (float4*)(sumT + ((size_t)b1 * 4096 + p) * 256 + h * 32);
    #pragma unroll
    for (int i = 0; i < 8; ++i) {
        float4 c = o4[i];
        c.x += acc[4 * i + 0]; c.y += acc[4 * i + 1];
        c.z += acc[4 * i + 2]; c.w += acc[4 * i + 3];
        o4[i] = c;
    }
}

// ---------------------------------------------------------------------------
// Kernel 5: output projection  out[b][o][p] = sum_c Wout[o][c] * S[b][p][c]
// ---------------------------------------------------------------------------
__global__ __launch_bounds__(256) void out_gemm_kernel(
    const float* __restrict__ sumT, const float* __restrict__ Wout,
    float* __restrict__ out)
{
    __shared__ float As[64][68];  // As[kk][m] = Wout[o0+m][k0+kk]
    __shared__ float Bs[64][68];  // Bs[kk][n] = S[b][p0+n][k0+kk]
    const int tid = threadIdx.x;
    const int tx = tid & 15, ty = tid >> 4;
    const int p0 = blockIdx.x * 64;
    const int o0 = blockIdx.y * 64;
    const int b  = blockIdx.z;

    const float* W = Wout + (size_t)o0 * 256;
    const float* S = sumT + (size_t)b * 4096 * 256 + (size_t)p0 * 256;

    float acc[4][4] = {};
    for (int k0 = 0; k0 < 256; k0 += 64) {
        {   // stage A
            const int m  = tid >> 4;
            const int kk = (tid & 15) * 4;
            #pragma unroll
            for (int l = 0; l < 4; ++l) {
                const int mm = m + l * 16;
                const float4 w4 = *(const float4*)&W[(size_t)mm * 256 + k0 + kk];
                As[kk + 0][mm] = w4.x; As[kk + 1][mm] = w4.y;
                As[kk + 2][mm] = w4.z; As[kk + 3][mm] = w4.w;
            }
        }
        {   // stage B: transpose rows of S into K-major
            const int n  = tid >> 2;
            const int kb2 = (tid & 3) * 16;
            const float* src = S + (size_t)n * 256 + k0 + kb2;
            #pragma unroll
            for (int u = 0; u < 4; ++u) {
                const float4 v = ((const float4*)src)[u];
                const int kk = kb2 + u * 4;
                Bs[kk + 0][n] = v.x; Bs[kk + 1][n] = v.y;
                Bs[kk + 2][n] = v.z; Bs[kk + 3][n] = v.w;
            }
        }
        __syncthreads();
        #pragma unroll 8
        for (int kk = 0; kk < 64; ++kk) {
            const float4 a  = *(const float4*)&As[kk][ty * 4];
            const float4 bv = *(const float4*)&Bs[kk][tx * 4];
            acc[0][0] += a.x * bv.x; acc[0][1] += a.x * bv.y; acc[0][2] += a.x * bv.z; acc[0][3] += a.x * bv.w;
            acc[1][0] += a.y * bv.x; acc[1][1] += a.y * bv.y; acc[1][2] += a.y * bv.z; acc[1][3] += a.y * bv.w;
            acc[2][0] += a.z * bv.x; acc[2][1] += a.z * bv.y; acc[2][2] += a.z * bv.z; acc[2][3] += a.z * bv.w;
            acc[3][0] += a.w * bv.x; acc[3][1] += a.w * bv.y; acc[3][2] += a.w * bv.z; acc[3][3] += a.w * bv.w;
        }
        __syncthreads();
    }
    float* ob = out + (size_t)b * 256 * 4096;
    #pragma unroll
    for (int oi = 0; oi < 4; ++oi) {
        const float4 v = make_float4(acc[oi][0], acc[oi][1], acc[oi][2], acc[oi][3]);
        *(float4*)&ob[(size_t)(o0 + ty * 4 + oi) * 4096 + p0 + tx * 4] = v;
    }
}

// ---------------------------------------------------------------------------
extern "C" void kernel_launch(void* const* d_in, const int* in_sizes, int n_in,
                              void* d_out, int out_size, void* d_ws, size_t ws_size,
                              hipStream_t stream)
{
    const float* x    = (const float*)d_in[0];
    const float* Wq   = (const float*)d_in[1];
    const float* Wkv  = (const float*)d_in[2];
    const float* Wqb  = (const float*)d_in[3];
    const float* Wkvb = (const float*)d_in[4];
    const float* Wout = (const float*)d_in[5];
    float* out = (float*)d_out;

    float* ws = (float*)d_ws;
    // workspace layout (floats):
    float* qT   = ws;                      // 4*4096*256  = 4,194,304  (becomes sum buffer)
    float* kvbT = qT + 4194304;            // 4*4096*512  = 8,388,608
    float* kT   = kvbT + 8388608;          // 4*1024*256  = 1,048,576
    float* vT   = kT + 1048576;            // 1,048,576
    // total ws floats = 14,680,064  (58.7 MB)
    float* qbT  = out;                     // reuse d_out as qb scratch (fully rewritten by final GEMM)

    proj_kernel<<<dim3(64, 16, 4), 256, 0, stream>>>(x, Wq, Wqb, Wkvb, qT, qbT, kvbT);
    convkv_kernel<<<dim3(16, 8, 4), 256, 0, stream>>>(x, Wkv, kT, vT);
    attn_img_kernel<<<dim3(16, 32), 256, 0, stream>>>(kT, vT, qT);
    attn_batch_kernel<<<dim3(512), 256, 0, stream>>>(qbT, kvbT, qT);
    out_gemm_kernel<<<dim3(64, 4, 4), 256, 0, stream>>>(qT, Wout, out);
}

// Round 2
// 331.587 us; speedup vs baseline: 1.9770x; 1.9770x over previous
//
#include <hip/hip_runtime.h>

#define ATTN_SCALE 0.17677669529663687f  // 32^-0.5

typedef __attribute__((ext_vector_type(8))) short bf16x8;
typedef __attribute__((ext_vector_type(4))) float f32x4;

__device__ inline unsigned short f2bf(float x) {
    unsigned int u = __float_as_uint(x);
    unsigned int r = u + 0x7fffu + ((u >> 16) & 1u);
    return (unsigned short)(r >> 16);
}
__device__ inline unsigned int pk2(float lo, float hi) {
    return (unsigned int)f2bf(lo) | ((unsigned int)f2bf(hi) << 16);
}
__device__ inline float bf2f(unsigned int u) { return __uint_as_float(u << 16); }

// ---------------------------------------------------------------------------
// Kernel 1: fused 1x1 projections.
//   q   -> qTb  bf16 [b][4096][256], pre-scaled by ATTN_SCALE
//   qb  -> qbT  fp32 [b][4096][256]  (d_out reuse)
//   kvb -> kvbT bf16 [b][4096][512]
// ---------------------------------------------------------------------------
__global__ __launch_bounds__(256) void proj_kernel(
    const float* __restrict__ x, const float* __restrict__ Wq,
    const float* __restrict__ Wqb, const float* __restrict__ Wkvb,
    ushort* __restrict__ qTb, float* __restrict__ qbT, ushort* __restrict__ kvbT)
{
    __shared__ float As[64][68];
    __shared__ float Bs[64][68];
    const int tid = threadIdx.x;
    const int tx = tid & 15, ty = tid >> 4;
    const int p0  = blockIdx.x * 64;
    const int oc0 = blockIdx.y * 64;
    const int b   = blockIdx.z;

    const float* W;
    if (oc0 < 256)      W = Wq   + (size_t)oc0 * 256;
    else if (oc0 < 512) W = Wqb  + (size_t)(oc0 - 256) * 256;
    else                W = Wkvb + (size_t)(oc0 - 512) * 256;

    const float* xb = x + (size_t)b * 256 * 4096 + p0;

    float acc[4][4] = {};
    for (int k0 = 0; k0 < 256; k0 += 64) {
        {
            const int m  = tid >> 4;
            const int kk = (tid & 15) * 4;
            #pragma unroll
            for (int l = 0; l < 4; ++l) {
                const int mm = m + l * 16;
                const float4 w4 = *(const float4*)&W[(size_t)mm * 256 + k0 + kk];
                As[kk + 0][mm] = w4.x; As[kk + 1][mm] = w4.y;
                As[kk + 2][mm] = w4.z; As[kk + 3][mm] = w4.w;
            }
        }
        {
            const int kk = tid >> 2;
            const int n  = (tid & 3) * 16;
            const float* src = xb + (size_t)(k0 + kk) * 4096 + n;
            float4* d4 = (float4*)&Bs[kk][n];
            d4[0] = ((const float4*)src)[0];
            d4[1] = ((const float4*)src)[1];
            d4[2] = ((const float4*)src)[2];
            d4[3] = ((const float4*)src)[3];
        }
        __syncthreads();
        #pragma unroll 8
        for (int kk = 0; kk < 64; ++kk) {
            const float4 a  = *(const float4*)&As[kk][ty * 4];
            const float4 bv = *(const float4*)&Bs[kk][tx * 4];
            acc[0][0] += a.x * bv.x; acc[0][1] += a.x * bv.y; acc[0][2] += a.x * bv.z; acc[0][3] += a.x * bv.w;
            acc[1][0] += a.y * bv.x; acc[1][1] += a.y * bv.y; acc[1][2] += a.y * bv.z; acc[1][3] += a.y * bv.w;
            acc[2][0] += a.z * bv.x; acc[2][1] += a.z * bv.y; acc[2][2] += a.z * bv.z; acc[2][3] += a.z * bv.w;
            acc[3][0] += a.w * bv.x; acc[3][1] += a.w * bv.y; acc[3][2] += a.w * bv.z; acc[3][3] += a.w * bv.w;
        }
        __syncthreads();
    }

    if (oc0 < 256) {            // q -> bf16, pre-scaled
        #pragma unroll
        for (int pj = 0; pj < 4; ++pj) {
            ushort4 v;
            v.x = f2bf(acc[0][pj] * ATTN_SCALE); v.y = f2bf(acc[1][pj] * ATTN_SCALE);
            v.z = f2bf(acc[2][pj] * ATTN_SCALE); v.w = f2bf(acc[3][pj] * ATTN_SCALE);
            *(ushort4*)&qTb[(size_t)(b * 4096 + p0 + tx * 4 + pj) * 256 + oc0 + ty * 4] = v;
        }
    } else if (oc0 < 512) {     // qb -> fp32
        #pragma unroll
        for (int pj = 0; pj < 4; ++pj) {
            const float4 v = make_float4(acc[0][pj], acc[1][pj], acc[2][pj], acc[3][pj]);
            *(float4*)&qbT[(size_t)(b * 4096 + p0 + tx * 4 + pj) * 256 + (oc0 - 256) + ty * 4] = v;
        }
    } else {                    // kvb -> bf16
        #pragma unroll
        for (int pj = 0; pj < 4; ++pj) {
            ushort4 v;
            v.x = f2bf(acc[0][pj]); v.y = f2bf(acc[1][pj]);
            v.z = f2bf(acc[2][pj]); v.w = f2bf(acc[3][pj]);
            *(ushort4*)&kvbT[(size_t)(b * 4096 + p0 + tx * 4 + pj) * 512 + (oc0 - 512) + ty * 4] = v;
        }
    }
}

// ---------------------------------------------------------------------------
// Kernel 2: 2x2 stride-2 conv -> K bf16 [b][1024][256], V transposed bf16
// vTt[(b*8+h)*32 + c][1024]
// ---------------------------------------------------------------------------
__global__ __launch_bounds__(256) void convkv_kernel(
    const float* __restrict__ x, const float* __restrict__ Wkv,
    ushort* __restrict__ kTb, ushort* __restrict__ vTtb)
{
    __shared__ float As[64][68];
    __shared__ float Bs[64][68];
    const int tid = threadIdx.x;
    const int tx = tid & 15, ty = tid >> 4;
    const int pp0 = blockIdx.x * 64;
    const int oc0 = blockIdx.y * 64;
    const int b   = blockIdx.z;

    const float* W  = Wkv + (size_t)oc0 * 1024;
    const float* xb = x + (size_t)b * 256 * 4096;

    float acc[4][4] = {};
    for (int k0 = 0; k0 < 1024; k0 += 64) {
        {
            const int m  = tid >> 4;
            const int kk = (tid & 15) * 4;
            #pragma unroll
            for (int l = 0; l < 4; ++l) {
                const int mm = m + l * 16;
                const float4 w4 = *(const float4*)&W[(size_t)mm * 1024 + k0 + kk];
                As[kk + 0][mm] = w4.x; As[kk + 1][mm] = w4.y;
                As[kk + 2][mm] = w4.z; As[kk + 3][mm] = w4.w;
            }
        }
        #pragma unroll
        for (int l = 0; l < 16; ++l) {
            const int e  = l * 256 + tid;
            const int kk = e >> 6, n = e & 63;
            const int kg = k0 + kk;
            const int c = kg >> 2, di = (kg >> 1) & 1, dj = kg & 1;
            const int pp = pp0 + n;
            const int i = pp >> 5, j = pp & 31;
            Bs[kk][n] = xb[(size_t)c * 4096 + (2 * i + di) * 64 + 2 * j + dj];
        }
        __syncthreads();
        #pragma unroll 8
        for (int kk = 0; kk < 64; ++kk) {
            const float4 a  = *(const float4*)&As[kk][ty * 4];
            const float4 bv = *(const float4*)&Bs[kk][tx * 4];
            acc[0][0] += a.x * bv.x; acc[0][1] += a.x * bv.y; acc[0][2] += a.x * bv.z; acc[0][3] += a.x * bv.w;
            acc[1][0] += a.y * bv.x; acc[1][1] += a.y * bv.y; acc[1][2] += a.y * bv.z; acc[1][3] += a.y * bv.w;
            acc[2][0] += a.z * bv.x; acc[2][1] += a.z * bv.y; acc[2][2] += a.z * bv.z; acc[2][3] += a.z * bv.w;
            acc[3][0] += a.w * bv.x; acc[3][1] += a.w * bv.y; acc[3][2] += a.w * bv.z; acc[3][3] += a.w * bv.w;
        }
        __syncthreads();
    }

    if (oc0 < 256) {  // K: [b][1024][256] bf16
        #pragma unroll
        for (int pj = 0; pj < 4; ++pj) {
            ushort4 v;
            v.x = f2bf(acc[0][pj]); v.y = f2bf(acc[1][pj]);
            v.z = f2bf(acc[2][pj]); v.w = f2bf(acc[3][pj]);
            *(ushort4*)&kTb[(size_t)(b * 1024 + pp0 + tx * 4 + pj) * 256 + oc0 + ty * 4] = v;
        }
    } else {          // V: transposed per (b,h,c) rows of 1024 positions
        #pragma unroll
        for (int oi = 0; oi < 4; ++oi) {
            const int o = oc0 - 256 + ty * 4 + oi;
            const int hh = o >> 5, c = o & 31;
            ushort4 v;
            v.x = f2bf(acc[oi][0]); v.y = f2bf(acc[oi][1]);
            v.z = f2bf(acc[oi][2]); v.w = f2bf(acc[oi][3]);
            *(ushort4*)&vTtb[((size_t)((b * 8 + hh) * 32 + c)) * 1024 + pp0 + tx * 4] = v;
        }
    }
}

// ---------------------------------------------------------------------------
// Kernel 3: spatial-reduction attention with bf16 MFMA (flash-style).
// Per block: one (b,h), 128 q-rows (4 waves x 32). KV staged in LDS, 128/tile.
// QK^T: mfma(K,Q) -> lane holds S[i=lane&15][j=16*st+4g+r].
// PV:   P permuted via 8 shuffles to A-frag layout; V read from transposed LDS.
// ---------------------------------------------------------------------------
__global__ __launch_bounds__(256) void attn_img_mfma(
    const ushort* __restrict__ qTb, const ushort* __restrict__ kTb,
    const ushort* __restrict__ vTtb, float* __restrict__ sumT)
{
    __shared__ ushort Ks[128][40];    // [pos][32ch + pad8]
    __shared__ ushort Vts[32][136];   // [ch][128pos + pad8]
    const int tid  = threadIdx.x;
    const int lane = tid & 63;
    const int wv   = tid >> 6;
    const int g    = lane >> 4, i16 = lane & 15;
    const int bh   = blockIdx.x;
    const int b    = bh >> 3, h = bh & 7;
    const int q0   = blockIdx.y * 128 + wv * 32;

    // hoisted Q fragments (pre-scaled bf16): lane holds Q[q0+it*16+i16][8g..8g+7]
    bf16x8 qf[2];
    #pragma unroll
    for (int it = 0; it < 2; ++it)
        qf[it] = *(const bf16x8*)(qTb + ((size_t)(b * 4096 + q0 + it * 16 + i16) * 256 + h * 32 + g * 8));

    f32x4 o[2][2] = {{{0.f,0.f,0.f,0.f},{0.f,0.f,0.f,0.f}},{{0.f,0.f,0.f,0.f},{0.f,0.f,0.f,0.f}}};
    float m[2] = {-3.0e38f, -3.0e38f};
    float l[2] = {0.f, 0.f};

    const ushort* kg = kTb + (size_t)b * 1024 * 256 + h * 32;
    const ushort* vg = vTtb + (size_t)bh * 32 * 1024;

    for (int kv0 = 0; kv0 < 1024; kv0 += 128) {
        // ---- stage K [128][32] and Vt [32][128] ----
        #pragma unroll
        for (int u = 0; u < 2; ++u) {
            const int chunk = tid + u * 256;
            const int r = chunk >> 2, q4 = chunk & 3;
            *(uint4*)&Ks[r][q4 * 8] = *(const uint4*)(kg + (size_t)(kv0 + r) * 256 + q4 * 8);
            const int c = chunk >> 4, sseg = chunk & 15;
            *(uint4*)&Vts[c][sseg * 8] = *(const uint4*)(vg + (size_t)c * 1024 + kv0 + sseg * 8);
        }
        __syncthreads();

        #pragma unroll
        for (int it = 0; it < 2; ++it) {
            // ---- QK^T: 8 subtiles of 16 j each ----
            f32x4 s[8];
            #pragma unroll
            for (int st = 0; st < 8; ++st) {
                const bf16x8 kf = *(const bf16x8*)&Ks[st * 16 + i16][g * 8];
                s[st] = __builtin_amdgcn_mfma_f32_16x16x32_bf16(kf, qf[it],
                        (f32x4){0.f, 0.f, 0.f, 0.f}, 0, 0, 0);
            }
            // ---- online softmax (row i16, stats lane-local after butterfly) ----
            float mt = -3.0e38f;
            #pragma unroll
            for (int st = 0; st < 8; ++st) {
                mt = fmaxf(mt, fmaxf(fmaxf(s[st][0], s[st][1]), fmaxf(s[st][2], s[st][3])));
            }
            mt = fmaxf(mt, __shfl_xor(mt, 16, 64));
            mt = fmaxf(mt, __shfl_xor(mt, 32, 64));
            const float mnew  = fmaxf(m[it], mt);
            const float alpha = __expf(m[it] - mnew);
            m[it] = mnew;
            float ls = 0.f;
            #pragma unroll
            for (int st = 0; st < 8; ++st) {
                #pragma unroll
                for (int r = 0; r < 4; ++r) {
                    const float p = __expf(s[st][r] - mnew);
                    s[st][r] = p; ls += p;
                }
            }
            ls += __shfl_xor(ls, 16, 64);
            ls += __shfl_xor(ls, 32, 64);
            l[it] = l[it] * alpha + ls;
            #pragma unroll
            for (int r = 0; r < 4; ++r) {
                const float ar = __shfl(alpha, 4 * g + r, 64);
                o[it][0][r] *= ar; o[it][1][r] *= ar;
            }
            // ---- P pack -> permute -> PV ----
            #pragma unroll
            for (int c4 = 0; c4 < 4; ++c4) {
                const unsigned int a0 = pk2(s[2 * c4][0], s[2 * c4][1]);
                const unsigned int a1 = pk2(s[2 * c4][2], s[2 * c4][3]);
                const unsigned int b0 = pk2(s[2 * c4 + 1][0], s[2 * c4 + 1][1]);
                const unsigned int b1 = pk2(s[2 * c4 + 1][2], s[2 * c4 + 1][3]);
                const int s0 = i16 + ((g & 1) << 5);
                const int s1 = s0 + 16;
                const unsigned int ta0 = __shfl(a0, s0, 64), tb0 = __shfl(b0, s0, 64);
                const unsigned int ta1 = __shfl(a1, s0, 64), tb1 = __shfl(b1, s0, 64);
                const unsigned int ua0 = __shfl(a0, s1, 64), ub0 = __shfl(b0, s1, 64);
                const unsigned int ua1 = __shfl(a1, s1, 64), ub1 = __shfl(b1, s1, 64);
                unsigned int wp[4];
                wp[0] = (g < 2) ? ta0 : tb0;
                wp[1] = (g < 2) ? ta1 : tb1;
                wp[2] = (g < 2) ? ua0 : ub0;
                wp[3] = (g < 2) ? ua1 : ub1;
                const bf16x8 pf = *(const bf16x8*)wp;   // lane: P[i16][jloc=8g+jj]
                #pragma unroll
                for (int ch = 0; ch < 2; ++ch) {
                    const bf16x8 vf = *(const bf16x8*)&Vts[ch * 16 + i16][c4 * 32 + g * 8];
                    o[it][ch] = __builtin_amdgcn_mfma_f32_16x16x32_bf16(pf, vf, o[it][ch], 0, 0, 0);
                }
            }
        }
        __syncthreads();
    }

    // ---- epilogue: normalize + write O (lane holds O[i=4g+r][c=16ch+i16]) ----
    #pragma unroll
    for (int it = 0; it < 2; ++it) {
        const float inv = 1.f / l[it];
        #pragma unroll
        for (int r = 0; r < 4; ++r) {
            const float fr = __shfl(inv, 4 * g + r, 64);
            const int row = q0 + it * 16 + 4 * g + r;
            float* dst = sumT + (size_t)(b * 4096 + row) * 256 + h * 32 + i16;
            dst[0]  = o[it][0][r] * fr;
            dst[16] = o[it][1][r] * fr;
        }
    }
}

// ---------------------------------------------------------------------------
// Kernel 4: batch-axis attention (bf16 k/v); adds into sum buffer.
// ---------------------------------------------------------------------------
__global__ __launch_bounds__(256) void attn_batch_kernel(
    const float* __restrict__ qbT, const ushort* __restrict__ kvbT,
    float* __restrict__ sumT)
{
    const int tid = threadIdx.x;
    const int b1 = tid & 3, h = (tid >> 2) & 7, pl = tid >> 5;
    const int p = blockIdx.x * 8 + pl;

    const float* qrow = qbT + ((size_t)b1 * 4096 + p) * 256 + h * 32;
    float q[32];
    #pragma unroll
    for (int i = 0; i < 8; ++i) {
        const float4 t = ((const float4*)qrow)[i];
        q[4 * i + 0] = t.x * ATTN_SCALE; q[4 * i + 1] = t.y * ATTN_SCALE;
        q[4 * i + 2] = t.z * ATTN_SCALE; q[4 * i + 3] = t.w * ATTN_SCALE;
    }

    float s[4];
    #pragma unroll
    for (int b2 = 0; b2 < 4; ++b2) {
        const uint4* k4 = (const uint4*)(kvbT + ((size_t)b2 * 4096 + p) * 512 + h * 32);
        float d = 0.f;
        #pragma unroll
        for (int i = 0; i < 4; ++i) {
            const uint4 w = k4[i];
            d += q[8 * i + 0] * bf2f(w.x & 0xffffu) + q[8 * i + 1] * bf2f(w.x >> 16);
            d += q[8 * i + 2] * bf2f(w.y & 0xffffu) + q[8 * i + 3] * bf2f(w.y >> 16);
            d += q[8 * i + 4] * bf2f(w.z & 0xffffu) + q[8 * i + 5] * bf2f(w.z >> 16);
            d += q[8 * i + 6] * bf2f(w.w & 0xffffu) + q[8 * i + 7] * bf2f(w.w >> 16);
        }
        s[b2] = d;
    }
    const float mx = fmaxf(fmaxf(s[0], s[1]), fmaxf(s[2], s[3]));
    float w[4];
    float lsum = 0.f;
    #pragma unroll
    for (int b2 = 0; b2 < 4; ++b2) { w[b2] = __expf(s[b2] - mx); lsum += w[b2]; }
    const float inv = 1.f / lsum;
    #pragma unroll
    for (int b2 = 0; b2 < 4; ++b2) w[b2] *= inv;

    float acc[32] = {};
    #pragma unroll
    for (int b2 = 0; b2 < 4; ++b2) {
        const uint4* v4 = (const uint4*)(kvbT + ((size_t)b2 * 4096 + p) * 512 + 256 + h * 32);
        const float wb = w[b2];
        #pragma unroll
        for (int i = 0; i < 4; ++i) {
            const uint4 vv = v4[i];
            acc[8 * i + 0] += wb * bf2f(vv.x & 0xffffu); acc[8 * i + 1] += wb * bf2f(vv.x >> 16);
            acc[8 * i + 2] += wb * bf2f(vv.y & 0xffffu); acc[8 * i + 3] += wb * bf2f(vv.y >> 16);
            acc[8 * i + 4] += wb * bf2f(vv.z & 0xffffu); acc[8 * i + 5] += wb * bf2f(vv.z >> 16);
            acc[8 * i + 6] += wb * bf2f(vv.w & 0xffffu); acc[8 * i + 7] += wb * bf2f(vv.w >> 16);
        }
    }
    float4* o4 = (float4*)(sumT + ((size_t)b1 * 4096 + p) * 256 + h * 32);
    #pragma unroll
    for (int i = 0; i < 8; ++i) {
        float4 c = o4[i];
        c.x += acc[4 * i + 0]; c.y += acc[4 * i + 1];
        c.z += acc[4 * i + 2]; c.w += acc[4 * i + 3];
        o4[i] = c;
    }
}

// ---------------------------------------------------------------------------
// Kernel 5: output projection  out[b][o][p] = sum_c Wout[o][c] * S[b][p][c]
// ---------------------------------------------------------------------------
__global__ __launch_bounds__(256) void out_gemm_kernel(
    const float* __restrict__ sumT, const float* __restrict__ Wout,
    float* __restrict__ out)
{
    __shared__ float As[64][68];
    __shared__ float Bs[64][68];
    const int tid = threadIdx.x;
    const int tx = tid & 15, ty = tid >> 4;
    const int p0 = blockIdx.x * 64;
    const int o0 = blockIdx.y * 64;
    const int b  = blockIdx.z;

    const float* W = Wout + (size_t)o0 * 256;
    const float* S = sumT + (size_t)b * 4096 * 256 + (size_t)p0 * 256;

    float acc[4][4] = {};
    for (int k0 = 0; k0 < 256; k0 += 64) {
        {
            const int m  = tid >> 4;
            const int kk = (tid & 15) * 4;
            #pragma unroll
            for (int l = 0; l < 4; ++l) {
                const int mm = m + l * 16;
                const float4 w4 = *(const float4*)&W[(size_t)mm * 256 + k0 + kk];
                As[kk + 0][mm] = w4.x; As[kk + 1][mm] = w4.y;
                As[kk + 2][mm] = w4.z; As[kk + 3][mm] = w4.w;
            }
        }
        {
            const int n  = tid >> 2;
            const int kb2 = (tid & 3) * 16;
            const float* src = S + (size_t)n * 256 + k0 + kb2;
            #pragma unroll
            for (int u = 0; u < 4; ++u) {
                const float4 v = ((const float4*)src)[u];
                const int kk = kb2 + u * 4;
                Bs[kk + 0][n] = v.x; Bs[kk + 1][n] = v.y;
                Bs[kk + 2][n] = v.z; Bs[kk + 3][n] = v.w;
            }
        }
        __syncthreads();
        #pragma unroll 8
        for (int kk = 0; kk < 64; ++kk) {
            const float4 a  = *(const float4*)&As[kk][ty * 4];
            const float4 bv = *(const float4*)&Bs[kk][tx * 4];
            acc[0][0] += a.x * bv.x; acc[0][1] += a.x * bv.y; acc[0][2] += a.x * bv.z; acc[0][3] += a.x * bv.w;
            acc[1][0] += a.y * bv.x; acc[1][1] += a.y * bv.y; acc[1][2] += a.y * bv.z; acc[1][3] += a.y * bv.w;
            acc[2][0] += a.z * bv.x; acc[2][1] += a.z * bv.y; acc[2][2] += a.z * bv.z; acc[2][3] += a.z * bv.w;
            acc[3][0] += a.w * bv.x; acc[3][1] += a.w * bv.y; acc[3][2] += a.w * bv.z; acc[3][3] += a.w * bv.w;
        }
        __syncthreads();
    }
    float* ob = out + (size_t)b * 256 * 4096;
    #pragma unroll
    for (int oi = 0; oi < 4; ++oi) {
        const float4 v = make_float4(acc[oi][0], acc[oi][1], acc[oi][2], acc[oi][3]);
        *(float4*)&ob[(size_t)(o0 + ty * 4 + oi) * 4096 + p0 + tx * 4] = v;
    }
}

// ---------------------------------------------------------------------------
extern "C" void kernel_launch(void* const* d_in, const int* in_sizes, int n_in,
                              void* d_out, int out_size, void* d_ws, size_t ws_size,
                              hipStream_t stream)
{
    const float* x    = (const float*)d_in[0];
    const float* Wq   = (const float*)d_in[1];
    const float* Wkv  = (const float*)d_in[2];
    const float* Wqb  = (const float*)d_in[3];
    const float* Wkvb = (const float*)d_in[4];
    const float* Wout = (const float*)d_in[5];
    float* out = (float*)d_out;

    float* ws = (float*)d_ws;
    // workspace layout:
    float*  sumT = ws;                          // 4*4096*256 fp32   = 16.78 MB
    ushort* kvbT = (ushort*)(ws + 4194304);     // 4*4096*512 bf16   = 16.78 MB
    ushort* qTb  = kvbT + 8388608;              // 4*4096*256 bf16   =  8.39 MB
    ushort* kTb  = qTb + 4194304;               // 4*1024*256 bf16   =  2.10 MB
    ushort* vTtb = kTb + 1048576;               // 4*8*32*1024 bf16  =  2.10 MB
    // total 46.1 MB
    float* qbT = out;                           // d_out reused as qb scratch (fp32)

    proj_kernel<<<dim3(64, 16, 4), 256, 0, stream>>>(x, Wq, Wqb, Wkvb, qTb, qbT, kvbT);
    convkv_kernel<<<dim3(16, 8, 4), 256, 0, stream>>>(x, Wkv, kTb, vTtb);
    attn_img_mfma<<<dim3(32, 32), 256, 0, stream>>>(qTb, kTb, vTtb, sumT);
    attn_batch_kernel<<<dim3(512), 256, 0, stream>>>(qbT, kvbT, sumT);
    out_gemm_kernel<<<dim3(64, 4, 4), 256, 0, stream>>>(sumT, Wout, out);
}

// Round 3
// 157.205 us; speedup vs baseline: 4.1700x; 2.1093x over previous
//
#include <hip/hip_runtime.h>

#define ATTN_SCALE 0.17677669529663687f  // 32^-0.5

typedef __attribute__((ext_vector_type(8))) short bf16x8;
typedef __attribute__((ext_vector_type(4))) float f32x4;

__device__ inline unsigned short f2bf(float x) {
    unsigned int u = __float_as_uint(x);
    unsigned int r = u + 0x7fffu + ((u >> 16) & 1u);
    return (unsigned short)(r >> 16);
}
__device__ inline unsigned int pk2(float lo, float hi) {
    return (unsigned int)f2bf(lo) | ((unsigned int)f2bf(hi) << 16);
}
__device__ inline float bf2f(unsigned int u) { return __uint_as_float(u << 16); }

// async 16B global->LDS (lds dest = wave-uniform base + lane*16)
#define GLDS16(gp, lp) \
    __builtin_amdgcn_global_load_lds((const __attribute__((address_space(1))) void*)(gp), \
                                     (__attribute__((address_space(3))) void*)(lp), 16, 0, 0)

// Stage a 128row x 64col bf16 tile into LDS (row-major, 64/row), XOR-swizzled:
// physical slot s holds logical slot s ^ (row&7). Pre-swizzle on the GLOBAL addr.
__device__ inline void stage_tile(const ushort* __restrict__ g, int rstride, int kofs,
                                  ushort* lbase, int w, int lane) {
    const int r0 = w * 32;
    #pragma unroll
    for (int u = 0; u < 4; ++u) {
        const int row  = r0 + u * 8 + (lane >> 3);
        const int slog = (lane & 7) ^ (row & 7);
        GLDS16(g + (size_t)row * rstride + kofs + slog * 8,
               lbase + (size_t)(r0 + u * 8) * 64);
    }
}

// read one 16B MFMA fragment (8 bf16, k-contig) honoring the swizzle
__device__ inline bf16x8 frag_ld(const ushort* t, int row, int slog) {
    return *(const bf16x8*)(t + row * 64 + ((slog ^ (row & 7)) * 8));
}

// one BK=64 MFMA step: 4x4 16x16 frags per wave, acc[fm][fp]
#define MFMA_STEP(WS_, XS_, WM_, WP_)                                                       \
    _Pragma("unroll")                                                                       \
    for (int kh = 0; kh < 2; ++kh) {                                                        \
        bf16x8 av[4], bvv[4];                                                               \
        _Pragma("unroll")                                                                   \
        for (int fm = 0; fm < 4; ++fm) av[fm]  = frag_ld(WS_, WM_ + fm * 16 + i16, kh * 4 + g); \
        _Pragma("unroll")                                                                   \
        for (int fp = 0; fp < 4; ++fp) bvv[fp] = frag_ld(XS_, WP_ + fp * 16 + i16, kh * 4 + g); \
        _Pragma("unroll")                                                                   \
        for (int fm = 0; fm < 4; ++fm)                                                      \
            _Pragma("unroll")                                                               \
            for (int fp = 0; fp < 4; ++fp)                                                  \
                acc[fm][fp] = __builtin_amdgcn_mfma_f32_16x16x32_bf16(av[fm], bvv[fp],      \
                                                                      acc[fm][fp], 0, 0, 0); \
    }

// ---------------------------------------------------------------------------
// cvt_x: xbfT[b][p][c] (bf16) = x[b][c][p], 64x64 LDS tile transpose
// ---------------------------------------------------------------------------
__global__ __launch_bounds__(256) void cvt_x_kernel(
    const float* __restrict__ x, ushort* __restrict__ xbfT)
{
    __shared__ float T[64][65];
    const int t = threadIdx.x;
    const int p0 = blockIdx.x * 64, c0 = blockIdx.y * 64, bb = blockIdx.z;
    const float* xb = x + ((size_t)bb * 256 + c0) * 4096 + p0;
    {
        const int cc = t >> 2, pq = (t & 3) * 16;
        #pragma unroll
        for (int u = 0; u < 4; ++u) {
            const float4 v = *(const float4*)&xb[(size_t)cc * 4096 + pq + u * 4];
            T[cc][pq + u * 4 + 0] = v.x; T[cc][pq + u * 4 + 1] = v.y;
            T[cc][pq + u * 4 + 2] = v.z; T[cc][pq + u * 4 + 3] = v.w;
        }
    }
    __syncthreads();
    {
        const int pp = t >> 2, cq = (t & 3) * 16;
        uint4 w0, w1;
        w0.x = pk2(T[cq + 0][pp],  T[cq + 1][pp]);  w0.y = pk2(T[cq + 2][pp],  T[cq + 3][pp]);
        w0.z = pk2(T[cq + 4][pp],  T[cq + 5][pp]);  w0.w = pk2(T[cq + 6][pp],  T[cq + 7][pp]);
        w1.x = pk2(T[cq + 8][pp],  T[cq + 9][pp]);  w1.y = pk2(T[cq + 10][pp], T[cq + 11][pp]);
        w1.z = pk2(T[cq + 12][pp], T[cq + 13][pp]); w1.w = pk2(T[cq + 14][pp], T[cq + 15][pp]);
        ushort* dst = xbfT + ((size_t)bb * 4096 + p0 + pp) * 256 + c0 + cq;
        *(uint4*)&dst[0] = w0;
        *(uint4*)&dst[8] = w1;
    }
}

// ---------------------------------------------------------------------------
// cvt_w: bf16 weight copies. Wallb[1024][256] = rows{Wq,Wqb,Wkvb};
//        Wkvbb[512][1024]; Woutb[256][256]
// ---------------------------------------------------------------------------
__global__ __launch_bounds__(256) void cvt_w_kernel(
    const float* __restrict__ Wq, const float* __restrict__ Wqb,
    const float* __restrict__ Wkvb, const float* __restrict__ Wkv,
    const float* __restrict__ Wout,
    ushort* __restrict__ Wallb, ushort* __restrict__ Wkvbb, ushort* __restrict__ Woutb)
{
    const int id = blockIdx.x * 256 + threadIdx.x;   // float4-chunk id
    const float* src; ushort* dst;
    if (id < 65536) {
        const int m = id >> 6, c4 = (id & 63) * 4;
        src = (m < 256) ? &Wq[(size_t)m * 256 + c4]
            : (m < 512) ? &Wqb[(size_t)(m - 256) * 256 + c4]
                        : &Wkvb[(size_t)(m - 512) * 256 + c4];
        dst = Wallb + (size_t)id * 4;
    } else if (id < 65536 + 131072) {
        const size_t el = (size_t)(id - 65536) * 4;
        src = &Wkv[el]; dst = Wkvbb + el;
    } else if (id < 65536 + 131072 + 16384) {
        const size_t el = (size_t)(id - 65536 - 131072) * 4;
        src = &Wout[el]; dst = Woutb + el;
    } else return;
    const float4 v = *(const float4*)src;
    ushort4 o; o.x = f2bf(v.x); o.y = f2bf(v.y); o.z = f2bf(v.z); o.w = f2bf(v.w);
    *(ushort4*)dst = o;
}

// ---------------------------------------------------------------------------
// cvt_xcol: im2col  xcol[b][pp][kk], kk = 4c+2di+dj, from xbfT
// ---------------------------------------------------------------------------
__global__ __launch_bounds__(256) void cvt_xcol_kernel(
    const ushort* __restrict__ xbfT, ushort* __restrict__ xcol)
{
    const int t = threadIdx.x;
    const int bb = blockIdx.y;
    const int pp = blockIdx.x * 4 + (t >> 6);
    const int c0 = (t & 63) * 4;
    const int i = pp >> 5, j = pp & 31;
    const int p00 = i * 128 + 2 * j;
    const ushort* xb = xbfT + (size_t)bb * 4096 * 256;
    const ushort4 r00 = *(const ushort4*)&xb[(size_t)(p00)      * 256 + c0];
    const ushort4 r01 = *(const ushort4*)&xb[(size_t)(p00 + 1)  * 256 + c0];
    const ushort4 r10 = *(const ushort4*)&xb[(size_t)(p00 + 64) * 256 + c0];
    const ushort4 r11 = *(const ushort4*)&xb[(size_t)(p00 + 65) * 256 + c0];
    uint4 w0, w1;
    w0.x = (uint)r00.x | ((uint)r01.x << 16); w0.y = (uint)r10.x | ((uint)r11.x << 16);
    w0.z = (uint)r00.y | ((uint)r01.y << 16); w0.w = (uint)r10.y | ((uint)r11.y << 16);
    w1.x = (uint)r00.z | ((uint)r01.z << 16); w1.y = (uint)r10.z | ((uint)r11.z << 16);
    w1.z = (uint)r00.w | ((uint)r01.w << 16); w1.w = (uint)r10.w | ((uint)r11.w << 16);
    ushort* dst = xcol + ((size_t)bb * 1024 + pp) * 1024 + (size_t)c0 * 4;
    *(uint4*)&dst[0] = w0;
    *(uint4*)&dst[8] = w1;
}

// ---------------------------------------------------------------------------
// proj_mfma: Y[m][p] = sum_c Wall[m][c] * x[c][p], M=1024,K=256,N=4096 per b.
// m<256 -> qTb (bf16, pre-scaled); <512 -> qbT fp32 (d_out); else kvbT bf16.
// ---------------------------------------------------------------------------
__global__ __launch_bounds__(256) void proj_mfma(
    const ushort* __restrict__ Wallb, const ushort* __restrict__ xbfT,
    ushort* __restrict__ qTb, float* __restrict__ qbT, ushort* __restrict__ kvbT)
{
    __shared__ __align__(16) ushort lds[16384];
    ushort* Ws = lds; ushort* Xs = lds + 8192;
    const int tid = threadIdx.x, lane = tid & 63, w = tid >> 6;
    const int g = lane >> 4, i16 = lane & 15;
    const int p0 = blockIdx.x * 128, m0 = blockIdx.y * 128, bb = blockIdx.z;
    const int wm = (w >> 1) * 64, wp = (w & 1) * 64;
    const ushort* Ag = Wallb + (size_t)m0 * 256;
    const ushort* Bg = xbfT + ((size_t)bb * 4096 + p0) * 256;
    f32x4 acc[4][4] = {};
    for (int ks = 0; ks < 4; ++ks) {
        stage_tile(Ag, 256, ks * 64, Ws, w, lane);
        stage_tile(Bg, 256, ks * 64, Xs, w, lane);
        __syncthreads();
        MFMA_STEP(Ws, Xs, wm, wp);
        __syncthreads();
    }
    #pragma unroll
    for (int fp = 0; fp < 4; ++fp) {
        const int p = p0 + wp + fp * 16 + i16;
        #pragma unroll
        for (int fm = 0; fm < 4; ++fm) {
            const int m = m0 + wm + fm * 16 + 4 * g;
            if (m0 < 256) {
                ushort4 v;
                v.x = f2bf(acc[fm][fp][0] * ATTN_SCALE); v.y = f2bf(acc[fm][fp][1] * ATTN_SCALE);
                v.z = f2bf(acc[fm][fp][2] * ATTN_SCALE); v.w = f2bf(acc[fm][fp][3] * ATTN_SCALE);
                *(ushort4*)&qTb[((size_t)bb * 4096 + p) * 256 + m] = v;
            } else if (m0 < 512) {
                const float4 v = make_float4(acc[fm][fp][0], acc[fm][fp][1],
                                             acc[fm][fp][2], acc[fm][fp][3]);
                *(float4*)&qbT[((size_t)bb * 4096 + p) * 256 + (m - 256)] = v;
            } else {
                ushort4 v;
                v.x = f2bf(acc[fm][fp][0]); v.y = f2bf(acc[fm][fp][1]);
                v.z = f2bf(acc[fm][fp][2]); v.w = f2bf(acc[fm][fp][3]);
                *(ushort4*)&kvbT[((size_t)bb * 4096 + p) * 512 + (m - 512)] = v;
            }
        }
    }
}

// ---------------------------------------------------------------------------
// conv_mfma: Y[m][pp] = sum_kk Wkv[m][kk]*xcol[pp][kk], M=512,K=1024,N=1024.
// m<256 -> kTb[b][pp][m]; else V -> LDS-transpose -> vTtb[(b,h,c)][pp]
// ---------------------------------------------------------------------------
__global__ __launch_bounds__(256) void conv_mfma(
    const ushort* __restrict__ Wkvbb, const ushort* __restrict__ xcol,
    ushort* __restrict__ kTb, ushort* __restrict__ vTtb)
{
    __shared__ __align__(16) ushort lds[16384];
    ushort* Ws = lds; ushort* Xs = lds + 8192;
    const int tid = threadIdx.x, lane = tid & 63, w = tid >> 6;
    const int g = lane >> 4, i16 = lane & 15;
    const int pp0 = blockIdx.x * 128, m0 = blockIdx.y * 128, bb = blockIdx.z;
    const int wm = (w >> 1) * 64, wp = (w & 1) * 64;
    const ushort* Ag = Wkvbb + (size_t)m0 * 1024;
    const ushort* Bg = xcol + ((size_t)bb * 1024 + pp0) * 1024;
    f32x4 acc[4][4] = {};
    for (int ks = 0; ks < 16; ++ks) {
        stage_tile(Ag, 1024, ks * 64, Ws, w, lane);
        stage_tile(Bg, 1024, ks * 64, Xs, w, lane);
        __syncthreads();
        MFMA_STEP(Ws, Xs, wm, wp);
        __syncthreads();
    }
    if (m0 < 256) {
        #pragma unroll
        for (int fp = 0; fp < 4; ++fp) {
            const int pp = pp0 + wp + fp * 16 + i16;
            #pragma unroll
            for (int fm = 0; fm < 4; ++fm) {
                const int m = m0 + wm + fm * 16 + 4 * g;
                ushort4 v;
                v.x = f2bf(acc[fm][fp][0]); v.y = f2bf(acc[fm][fp][1]);
                v.z = f2bf(acc[fm][fp][2]); v.w = f2bf(acc[fm][fp][3]);
                *(ushort4*)&kTb[((size_t)bb * 1024 + pp) * 256 + m] = v;
            }
        }
    } else {
        // transpose 128(m) x 128(pp) through LDS, then coalesced rows out
        ushort (*T)[128] = (ushort(*)[128])lds;
        #pragma unroll
        for (int fm = 0; fm < 4; ++fm)
            #pragma unroll
            for (int fp = 0; fp < 4; ++fp)
                #pragma unroll
                for (int r = 0; r < 4; ++r)
                    T[wm + fm * 16 + 4 * g + r][wp + fp * 16 + i16] = f2bf(acc[fm][fp][r]);
        __syncthreads();
        #pragma unroll
        for (int u = 0; u < 8; ++u) {
            const int chunk = u * 256 + tid;
            const int row = chunk >> 4, slot = chunk & 15;
            const int mg = m0 - 256 + row;
            const int hh = mg >> 5, cc = mg & 31;
            const uint4 val = *(uint4*)&T[row][slot * 8];
            *(uint4*)&vTtb[((size_t)(bb * 8 + hh) * 32 + cc) * 1024 + pp0 + slot * 8] = val;
        }
    }
}

// ---------------------------------------------------------------------------
// out_mfma: out[b][o][p] = sum_c Wout[o][c]*sumT[b][p][c]. A=S(p rows), B=W.
// ---------------------------------------------------------------------------
__global__ __launch_bounds__(256) void out_mfma(
    const float* __restrict__ sumT, const ushort* __restrict__ Woutb,
    float* __restrict__ out)
{
    __shared__ __align__(16) ushort lds[16384];
    ushort* Ss = lds; ushort* Wo = lds + 8192;
    const int tid = threadIdx.x, lane = tid & 63, w = tid >> 6;
    const int g = lane >> 4, i16 = lane & 15;
    const int p0 = blockIdx.x * 128, o0 = blockIdx.y * 128, bb = blockIdx.z;
    const int wpp = (w >> 1) * 64, wo = (w & 1) * 64;
    const float* Sg = sumT + ((size_t)bb * 4096 + p0) * 256;
    const ushort* Bgw = Woutb + (size_t)o0 * 256;
    const int srow = tid >> 1, shalf = tid & 1;
    f32x4 acc[4][4] = {};
    for (int ks = 0; ks < 4; ++ks) {
        {   // reg-stage A: fp32 -> bf16, swizzled ds_write
            const float* src = Sg + (size_t)srow * 256 + ks * 64 + shalf * 32;
            #pragma unroll
            for (int jj = 0; jj < 4; ++jj) {
                const float4 f0 = *(const float4*)&src[jj * 8];
                const float4 f1 = *(const float4*)&src[jj * 8 + 4];
                uint4 pk;
                pk.x = pk2(f0.x, f0.y); pk.y = pk2(f0.z, f0.w);
                pk.z = pk2(f1.x, f1.y); pk.w = pk2(f1.z, f1.w);
                const int slog = shalf * 4 + jj;
                const int sp = slog ^ (srow & 7);
                *(uint4*)&Ss[(size_t)srow * 64 + sp * 8] = pk;
            }
        }
        stage_tile(Bgw, 256, ks * 64, Wo, w, lane);
        __syncthreads();
        MFMA_STEP(Ss, Wo, wpp, wo);
        __syncthreads();
    }
    #pragma unroll
    for (int fo = 0; fo < 4; ++fo) {
        const int o = o0 + wo + fo * 16 + i16;
        #pragma unroll
        for (int fp = 0; fp < 4; ++fp) {
            const int p = p0 + wpp + fp * 16 + 4 * g;
            const float4 v = make_float4(acc[fp][fo][0], acc[fp][fo][1],
                                         acc[fp][fo][2], acc[fp][fo][3]);
            *(float4*)&out[(size_t)bb * 1048576 + (size_t)o * 4096 + p] = v;
        }
    }
}

// ---------------------------------------------------------------------------
// attn_img_mfma: unchanged from R2 (verified)
// ---------------------------------------------------------------------------
__global__ __launch_bounds__(256) void attn_img_mfma(
    const ushort* __restrict__ qTb, const ushort* __restrict__ kTb,
    const ushort* __restrict__ vTtb, float* __restrict__ sumT)
{
    __shared__ ushort Ks[128][40];
    __shared__ ushort Vts[32][136];
    const int tid  = threadIdx.x;
    const int lane = tid & 63;
    const int wv   = tid >> 6;
    const int g    = lane >> 4, i16 = lane & 15;
    const int bh   = blockIdx.x;
    const int b    = bh >> 3, h = bh & 7;
    const int q0   = blockIdx.y * 128 + wv * 32;

    bf16x8 qf[2];
    #pragma unroll
    for (int it = 0; it < 2; ++it)
        qf[it] = *(const bf16x8*)(qTb + ((size_t)(b * 4096 + q0 + it * 16 + i16) * 256 + h * 32 + g * 8));

    f32x4 o[2][2] = {{{0.f,0.f,0.f,0.f},{0.f,0.f,0.f,0.f}},{{0.f,0.f,0.f,0.f},{0.f,0.f,0.f,0.f}}};
    float m[2] = {-3.0e38f, -3.0e38f};
    float l[2] = {0.f, 0.f};

    const ushort* kg = kTb + (size_t)b * 1024 * 256 + h * 32;
    const ushort* vg = vTtb + (size_t)bh * 32 * 1024;

    for (int kv0 = 0; kv0 < 1024; kv0 += 128) {
        #pragma unroll
        for (int u = 0; u < 2; ++u) {
            const int chunk = tid + u * 256;
            const int r = chunk >> 2, q4 = chunk & 3;
            *(uint4*)&Ks[r][q4 * 8] = *(const uint4*)(kg + (size_t)(kv0 + r) * 256 + q4 * 8);
            const int c = chunk >> 4, sseg = chunk & 15;
            *(uint4*)&Vts[c][sseg * 8] = *(const uint4*)(vg + (size_t)c * 1024 + kv0 + sseg * 8);
        }
        __syncthreads();

        #pragma unroll
        for (int it = 0; it < 2; ++it) {
            f32x4 s[8];
            #pragma unroll
            for (int st = 0; st < 8; ++st) {
                const bf16x8 kf = *(const bf16x8*)&Ks[st * 16 + i16][g * 8];
                s[st] = __builtin_amdgcn_mfma_f32_16x16x32_bf16(kf, qf[it],
                        (f32x4){0.f, 0.f, 0.f, 0.f}, 0, 0, 0);
            }
            float mt = -3.0e38f;
            #pragma unroll
            for (int st = 0; st < 8; ++st)
                mt = fmaxf(mt, fmaxf(fmaxf(s[st][0], s[st][1]), fmaxf(s[st][2], s[st][3])));
            mt = fmaxf(mt, __shfl_xor(mt, 16, 64));
            mt = fmaxf(mt, __shfl_xor(mt, 32, 64));
            const float mnew  = fmaxf(m[it], mt);
            const float alpha = __expf(m[it] - mnew);
            m[it] = mnew;
            float ls = 0.f;
            #pragma unroll
            for (int st = 0; st < 8; ++st) {
                #pragma unroll
                for (int r = 0; r < 4; ++r) {
                    const float p = __expf(s[st][r] - mnew);
                    s[st][r] = p; ls += p;
                }
            }
            ls += __shfl_xor(ls, 16, 64);
            ls += __shfl_xor(ls, 32, 64);
            l[it] = l[it] * alpha + ls;
            #pragma unroll
            for (int r = 0; r < 4; ++r) {
                const float ar = __shfl(alpha, 4 * g + r, 64);
                o[it][0][r] *= ar; o[it][1][r] *= ar;
            }
            #pragma unroll
            for (int c4 = 0; c4 < 4; ++c4) {
                const unsigned int a0 = pk2(s[2 * c4][0], s[2 * c4][1]);
                const unsigned int a1 = pk2(s[2 * c4][2], s[2 * c4][3]);
                const unsigned int b0 = pk2(s[2 * c4 + 1][0], s[2 * c4 + 1][1]);
                const unsigned int b1 = pk2(s[2 * c4 + 1][2], s[2 * c4 + 1][3]);
                const int s0 = i16 + ((g & 1) << 5);
                const int s1 = s0 + 16;
                const unsigned int ta0 = __shfl(a0, s0, 64), tb0 = __shfl(b0, s0, 64);
                const unsigned int ta1 = __shfl(a1, s0, 64), tb1 = __shfl(b1, s0, 64);
                const unsigned int ua0 = __shfl(a0, s1, 64), ub0 = __shfl(b0, s1, 64);
                const unsigned int ua1 = __shfl(a1, s1, 64), ub1 = __shfl(b1, s1, 64);
                unsigned int wp[4];
                wp[0] = (g < 2) ? ta0 : tb0;
                wp[1] = (g < 2) ? ta1 : tb1;
                wp[2] = (g < 2) ? ua0 : ub0;
                wp[3] = (g < 2) ? ua1 : ub1;
                const bf16x8 pf = *(const bf16x8*)wp;
                #pragma unroll
                for (int ch = 0; ch < 2; ++ch) {
                    const bf16x8 vf = *(const bf16x8*)&Vts[ch * 16 + i16][c4 * 32 + g * 8];
                    o[it][ch] = __builtin_amdgcn_mfma_f32_16x16x32_bf16(pf, vf, o[it][ch], 0, 0, 0);
                }
            }
        }
        __syncthreads();
    }

    #pragma unroll
    for (int it = 0; it < 2; ++it) {
        const float inv = 1.f / l[it];
        #pragma unroll
        for (int r = 0; r < 4; ++r) {
            const float fr = __shfl(inv, 4 * g + r, 64);
            const int row = q0 + it * 16 + 4 * g + r;
            float* dst = sumT + (size_t)(b * 4096 + row) * 256 + h * 32 + i16;
            dst[0]  = o[it][0][r] * fr;
            dst[16] = o[it][1][r] * fr;
        }
    }
}

// ---------------------------------------------------------------------------
// attn_batch: unchanged from R2
// ---------------------------------------------------------------------------
__global__ __launch_bounds__(256) void attn_batch_kernel(
    const float* __restrict__ qbT, const ushort* __restrict__ kvbT,
    float* __restrict__ sumT)
{
    const int tid = threadIdx.x;
    const int b1 = tid & 3, h = (tid >> 2) & 7, pl = tid >> 5;
    const int p = blockIdx.x * 8 + pl;

    const float* qrow = qbT + ((size_t)b1 * 4096 + p) * 256 + h * 32;
    float q[32];
    #pragma unroll
    for (int i = 0; i < 8; ++i) {
        const float4 t = ((const float4*)qrow)[i];
        q[4 * i + 0] = t.x * ATTN_SCALE; q[4 * i + 1] = t.y * ATTN_SCALE;
        q[4 * i + 2] = t.z * ATTN_SCALE; q[4 * i + 3] = t.w * ATTN_SCALE;
    }

    float s[4];
    #pragma unroll
    for (int b2 = 0; b2 < 4; ++b2) {
        const uint4* k4 = (const uint4*)(kvbT + ((size_t)b2 * 4096 + p) * 512 + h * 32);
        float d = 0.f;
        #pragma unroll
        for (int i = 0; i < 4; ++i) {
            const uint4 w = k4[i];
            d += q[8 * i + 0] * bf2f(w.x & 0xffffu) + q[8 * i + 1] * bf2f(w.x >> 16);
            d += q[8 * i + 2] * bf2f(w.y & 0xffffu) + q[8 * i + 3] * bf2f(w.y >> 16);
            d += q[8 * i + 4] * bf2f(w.z & 0xffffu) + q[8 * i + 5] * bf2f(w.z >> 16);
            d += q[8 * i + 6] * bf2f(w.w & 0xffffu) + q[8 * i + 7] * bf2f(w.w >> 16);
        }
        s[b2] = d;
    }
    const float mx = fmaxf(fmaxf(s[0], s[1]), fmaxf(s[2], s[3]));
    float w[4];
    float lsum = 0.f;
    #pragma unroll
    for (int b2 = 0; b2 < 4; ++b2) { w[b2] = __expf(s[b2] - mx); lsum += w[b2]; }
    const float inv = 1.f / lsum;
    #pragma unroll
    for (int b2 = 0; b2 < 4; ++b2) w[b2] *= inv;

    float acc[32] = {};
    #pragma unroll
    for (int b2 = 0; b2 < 4; ++b2) {
        const uint4* v4 = (const uint4*)(kvbT + ((size_t)b2 * 4096 + p) * 512 + 256 + h * 32);
        const float wb = w[b2];
        #pragma unroll
        for (int i = 0; i < 4; ++i) {
            const uint4 vv = v4[i];
            acc[8 * i + 0] += wb * bf2f(vv.x & 0xffffu); acc[8 * i + 1] += wb * bf2f(vv.x >> 16);
            acc[8 * i + 2] += wb * bf2f(vv.y & 0xffffu); acc[8 * i + 3] += wb * bf2f(vv.y >> 16);
            acc[8 * i + 4] += wb * bf2f(vv.z & 0xffffu); acc[8 * i + 5] += wb * bf2f(vv.z >> 16);
            acc[8 * i + 6] += wb * bf2f(vv.w & 0xffffu); acc[8 * i + 7] += wb * bf2f(vv.w >> 16);
        }
    }
    float4* o4 = (float4*)(sumT + ((size_t)b1 * 4096 + p) * 256 + h * 32);
    #pragma unroll
    for (int i = 0; i < 8; ++i) {
        float4 c = o4[i];
        c.x += acc[4 * i + 0]; c.y += acc[4 * i + 1];
        c.z += acc[4 * i + 2]; c.w += acc[4 * i + 3];
        o4[i] = c;
    }
}

// ---------------------------------------------------------------------------
extern "C" void kernel_launch(void* const* d_in, const int* in_sizes, int n_in,
                              void* d_out, int out_size, void* d_ws, size_t ws_size,
                              hipStream_t stream)
{
    const float* x    = (const float*)d_in[0];
    const float* Wq   = (const float*)d_in[1];
    const float* Wkv  = (const float*)d_in[2];
    const float* Wqb  = (const float*)d_in[3];
    const float* Wkvb = (const float*)d_in[4];
    const float* Wout = (const float*)d_in[5];
    float* out = (float*)d_out;

    // workspace (ushort units). sumT (fp32, 16.78MB) aliases xbfT+xcol, which
    // are dead before attn_img writes sumT. Total: 47.8 MB.
    ushort* base  = (ushort*)d_ws;
    ushort* xbfT  = base;                    // 4,194,304
    ushort* xcol  = base + 4194304;          // 4,194,304
    ushort* Wallb = base + 8388608;          //   262,144
    ushort* Wkvbb = base + 8650752;          //   524,288
    float*  sumT  = (float*)base;            // aliases [0, 8388608) ushorts
    ushort* qTb   = base + 9175040;          // 4,194,304
    ushort* kvbT  = base + 13369344;         // 8,388,608
    ushort* kTb   = base + 21757952;         // 1,048,576
    ushort* vTtb  = base + 22806528;         // 1,048,576
    ushort* Woutb = base + 23855104;         //    65,536
    float* qbT = out;                        // d_out reused as qb scratch

    cvt_x_kernel<<<dim3(64, 4, 4), 256, 0, stream>>>(x, xbfT);
    cvt_w_kernel<<<dim3(832), 256, 0, stream>>>(Wq, Wqb, Wkvb, Wkv, Wout, Wallb, Wkvbb, Woutb);
    cvt_xcol_kernel<<<dim3(256, 4), 256, 0, stream>>>(xbfT, xcol);
    proj_mfma<<<dim3(32, 8, 4), 256, 0, stream>>>(Wallb, xbfT, qTb, qbT, kvbT);
    conv_mfma<<<dim3(8, 4, 4), 256, 0, stream>>>(Wkvbb, xcol, kTb, vTtb);
    attn_img_mfma<<<dim3(32, 32), 256, 0, stream>>>(qTb, kTb, vTtb, sumT);
    attn_batch_kernel<<<dim3(512), 256, 0, stream>>>(qbT, kvbT, sumT);
    out_mfma<<<dim3(32, 2, 4), 256, 0, stream>>>(sumT, Woutb, out);
}

// Round 4
// 131.274 us; speedup vs baseline: 4.9937x; 1.1975x over previous
//
#include <hip/hip_runtime.h>

#define ATTN_SCALE 0.17677669529663687f  // 32^-0.5

typedef __attribute__((ext_vector_type(8))) short bf16x8;
typedef __attribute__((ext_vector_type(4))) float f32x4;
typedef __attribute__((ext_vector_type(16))) float f32x16;

__device__ inline unsigned short f2bf(float x) {
    unsigned int u = __float_as_uint(x);
    unsigned int r = u + 0x7fffu + ((u >> 16) & 1u);
    return (unsigned short)(r >> 16);
}
__device__ inline unsigned int pk2(float lo, float hi) {
    return (unsigned int)f2bf(lo) | ((unsigned int)f2bf(hi) << 16);
}
__device__ inline float bf2f(unsigned int u) { return __uint_as_float(u << 16); }

// async 16B global->LDS (lds dest = wave-uniform base + lane*16)
#define GLDS16(gp, lp) \
    __builtin_amdgcn_global_load_lds((const __attribute__((address_space(1))) void*)(gp), \
                                     (__attribute__((address_space(3))) void*)(lp), 16, 0, 0)

// Stage a 128row x 64col bf16 tile into LDS (row-major, 64/row), XOR-swizzled:
// physical slot s holds logical slot s ^ (row&7). Pre-swizzle on the GLOBAL addr.
__device__ inline void stage_tile(const ushort* __restrict__ g, int rstride, int kofs,
                                  ushort* lbase, int w, int lane) {
    const int r0 = w * 32;
    #pragma unroll
    for (int u = 0; u < 4; ++u) {
        const int row  = r0 + u * 8 + (lane >> 3);
        const int slog = (lane & 7) ^ (row & 7);
        GLDS16(g + (size_t)row * rstride + kofs + slog * 8,
               lbase + (size_t)(r0 + u * 8) * 64);
    }
}

// read one 16B MFMA fragment (8 bf16, k-contig) honoring the swizzle
__device__ inline bf16x8 frag_ld(const ushort* t, int row, int slog) {
    return *(const bf16x8*)(t + row * 64 + ((slog ^ (row & 7)) * 8));
}

// one BK=64 MFMA step: 4x4 16x16 frags per wave, acc[fm][fp]
#define MFMA_STEP(WS_, XS_, WM_, WP_)                                                       \
    _Pragma("unroll")                                                                       \
    for (int kh = 0; kh < 2; ++kh) {                                                        \
        bf16x8 av[4], bvv[4];                                                               \
        _Pragma("unroll")                                                                   \
        for (int fm = 0; fm < 4; ++fm) av[fm]  = frag_ld(WS_, WM_ + fm * 16 + i16, kh * 4 + g); \
        _Pragma("unroll")                                                                   \
        for (int fp = 0; fp < 4; ++fp) bvv[fp] = frag_ld(XS_, WP_ + fp * 16 + i16, kh * 4 + g); \
        _Pragma("unroll")                                                                   \
        for (int fm = 0; fm < 4; ++fm)                                                      \
            _Pragma("unroll")                                                               \
            for (int fp = 0; fp < 4; ++fp)                                                  \
                acc[fm][fp] = __builtin_amdgcn_mfma_f32_16x16x32_bf16(av[fm], bvv[fp],      \
                                                                      acc[fm][fp], 0, 0, 0); \
    }

// ---------------------------------------------------------------------------
// cvt_x: xbfT[b][p][c] (bf16) = x[b][c][p], 64x64 LDS tile transpose
// ---------------------------------------------------------------------------
__global__ __launch_bounds__(256) void cvt_x_kernel(
    const float* __restrict__ x, ushort* __restrict__ xbfT)
{
    __shared__ float T[64][65];
    const int t = threadIdx.x;
    const int p0 = blockIdx.x * 64, c0 = blockIdx.y * 64, bb = blockIdx.z;
    const float* xb = x + ((size_t)bb * 256 + c0) * 4096 + p0;
    {
        const int cc = t >> 2, pq = (t & 3) * 16;
        #pragma unroll
        for (int u = 0; u < 4; ++u) {
            const float4 v = *(const float4*)&xb[(size_t)cc * 4096 + pq + u * 4];
            T[cc][pq + u * 4 + 0] = v.x; T[cc][pq + u * 4 + 1] = v.y;
            T[cc][pq + u * 4 + 2] = v.z; T[cc][pq + u * 4 + 3] = v.w;
        }
    }
    __syncthreads();
    {
        const int pp = t >> 2, cq = (t & 3) * 16;
        uint4 w0, w1;
        w0.x = pk2(T[cq + 0][pp],  T[cq + 1][pp]);  w0.y = pk2(T[cq + 2][pp],  T[cq + 3][pp]);
        w0.z = pk2(T[cq + 4][pp],  T[cq + 5][pp]);  w0.w = pk2(T[cq + 6][pp],  T[cq + 7][pp]);
        w1.x = pk2(T[cq + 8][pp],  T[cq + 9][pp]);  w1.y = pk2(T[cq + 10][pp], T[cq + 11][pp]);
        w1.z = pk2(T[cq + 12][pp], T[cq + 13][pp]); w1.w = pk2(T[cq + 14][pp], T[cq + 15][pp]);
        ushort* dst = xbfT + ((size_t)bb * 4096 + p0 + pp) * 256 + c0 + cq;
        *(uint4*)&dst[0] = w0;
        *(uint4*)&dst[8] = w1;
    }
}

// ---------------------------------------------------------------------------
// cvt_w: bf16 weight copies. Wallb[1024][256] = rows{Wq,Wqb,Wkvb};
//        Wkvbb[512][1024]; Woutb[256][256]
// ---------------------------------------------------------------------------
__global__ __launch_bounds__(256) void cvt_w_kernel(
    const float* __restrict__ Wq, const float* __restrict__ Wqb,
    const float* __restrict__ Wkvb, const float* __restrict__ Wkv,
    const float* __restrict__ Wout,
    ushort* __restrict__ Wallb, ushort* __restrict__ Wkvbb, ushort* __restrict__ Woutb)
{
    const int id = blockIdx.x * 256 + threadIdx.x;   // float4-chunk id
    const float* src; ushort* dst;
    if (id < 65536) {
        const int m = id >> 6, c4 = (id & 63) * 4;
        src = (m < 256) ? &Wq[(size_t)m * 256 + c4]
            : (m < 512) ? &Wqb[(size_t)(m - 256) * 256 + c4]
                        : &Wkvb[(size_t)(m - 512) * 256 + c4];
        dst = Wallb + (size_t)id * 4;
    } else if (id < 65536 + 131072) {
        const size_t el = (size_t)(id - 65536) * 4;
        src = &Wkv[el]; dst = Wkvbb + el;
    } else if (id < 65536 + 131072 + 16384) {
        const size_t el = (size_t)(id - 65536 - 131072) * 4;
        src = &Wout[el]; dst = Woutb + el;
    } else return;
    const float4 v = *(const float4*)src;
    ushort4 o; o.x = f2bf(v.x); o.y = f2bf(v.y); o.z = f2bf(v.z); o.w = f2bf(v.w);
    *(ushort4*)dst = o;
}

// ---------------------------------------------------------------------------
// cvt_xcol: im2col  xcol[b][pp][kk], kk = 4c+2di+dj, from xbfT
// ---------------------------------------------------------------------------
__global__ __launch_bounds__(256) void cvt_xcol_kernel(
    const ushort* __restrict__ xbfT, ushort* __restrict__ xcol)
{
    const int t = threadIdx.x;
    const int bb = blockIdx.y;
    const int pp = blockIdx.x * 4 + (t >> 6);
    const int c0 = (t & 63) * 4;
    const int i = pp >> 5, j = pp & 31;
    const int p00 = i * 128 + 2 * j;
    const ushort* xb = xbfT + (size_t)bb * 4096 * 256;
    const ushort4 r00 = *(const ushort4*)&xb[(size_t)(p00)      * 256 + c0];
    const ushort4 r01 = *(const ushort4*)&xb[(size_t)(p00 + 1)  * 256 + c0];
    const ushort4 r10 = *(const ushort4*)&xb[(size_t)(p00 + 64) * 256 + c0];
    const ushort4 r11 = *(const ushort4*)&xb[(size_t)(p00 + 65) * 256 + c0];
    uint4 w0, w1;
    w0.x = (uint)r00.x | ((uint)r01.x << 16); w0.y = (uint)r10.x | ((uint)r11.x << 16);
    w0.z = (uint)r00.y | ((uint)r01.y << 16); w0.w = (uint)r10.y | ((uint)r11.y << 16);
    w1.x = (uint)r00.z | ((uint)r01.z << 16); w1.y = (uint)r10.z | ((uint)r11.z << 16);
    w1.z = (uint)r00.w | ((uint)r01.w << 16); w1.w = (uint)r10.w | ((uint)r11.w << 16);
    ushort* dst = xcol + ((size_t)bb * 1024 + pp) * 1024 + (size_t)c0 * 4;
    *(uint4*)&dst[0] = w0;
    *(uint4*)&dst[8] = w1;
}

// ---------------------------------------------------------------------------
// proj_mfma: Y[m][p] = sum_c Wall[m][c] * x[c][p], M=1024,K=256,N=4096 per b.
// m<256 -> qTb (bf16, pre-scaled); <512 -> qbT fp32 (d_out); else kvbT bf16.
// ---------------------------------------------------------------------------
__global__ __launch_bounds__(256) void proj_mfma(
    const ushort* __restrict__ Wallb, const ushort* __restrict__ xbfT,
    ushort* __restrict__ qTb, float* __restrict__ qbT, ushort* __restrict__ kvbT)
{
    __shared__ __align__(16) ushort lds[16384];
    ushort* Ws = lds; ushort* Xs = lds + 8192;
    const int tid = threadIdx.x, lane = tid & 63, w = tid >> 6;
    const int g = lane >> 4, i16 = lane & 15;
    const int p0 = blockIdx.x * 128, m0 = blockIdx.y * 128, bb = blockIdx.z;
    const int wm = (w >> 1) * 64, wp = (w & 1) * 64;
    const ushort* Ag = Wallb + (size_t)m0 * 256;
    const ushort* Bg = xbfT + ((size_t)bb * 4096 + p0) * 256;
    f32x4 acc[4][4] = {};
    for (int ks = 0; ks < 4; ++ks) {
        stage_tile(Ag, 256, ks * 64, Ws, w, lane);
        stage_tile(Bg, 256, ks * 64, Xs, w, lane);
        __syncthreads();
        MFMA_STEP(Ws, Xs, wm, wp);
        __syncthreads();
    }
    #pragma unroll
    for (int fp = 0; fp < 4; ++fp) {
        const int p = p0 + wp + fp * 16 + i16;
        #pragma unroll
        for (int fm = 0; fm < 4; ++fm) {
            const int m = m0 + wm + fm * 16 + 4 * g;
            if (m0 < 256) {
                ushort4 v;
                v.x = f2bf(acc[fm][fp][0] * ATTN_SCALE); v.y = f2bf(acc[fm][fp][1] * ATTN_SCALE);
                v.z = f2bf(acc[fm][fp][2] * ATTN_SCALE); v.w = f2bf(acc[fm][fp][3] * ATTN_SCALE);
                *(ushort4*)&qTb[((size_t)bb * 4096 + p) * 256 + m] = v;
            } else if (m0 < 512) {
                const float4 v = make_float4(acc[fm][fp][0], acc[fm][fp][1],
                                             acc[fm][fp][2], acc[fm][fp][3]);
                *(float4*)&qbT[((size_t)bb * 4096 + p) * 256 + (m - 256)] = v;
            } else {
                ushort4 v;
                v.x = f2bf(acc[fm][fp][0]); v.y = f2bf(acc[fm][fp][1]);
                v.z = f2bf(acc[fm][fp][2]); v.w = f2bf(acc[fm][fp][3]);
                *(ushort4*)&kvbT[((size_t)bb * 4096 + p) * 512 + (m - 512)] = v;
            }
        }
    }
}

// ---------------------------------------------------------------------------
// conv_mfma: Y[m][pp] = sum_kk Wkv[m][kk]*xcol[pp][kk], M=512,K=1024,N=1024.
// m<256 -> kTb[b][pp][m]; else V -> LDS-transpose -> vTtb[(b,h,c)][pp]
// ---------------------------------------------------------------------------
__global__ __launch_bounds__(256) void conv_mfma(
    const ushort* __restrict__ Wkvbb, const ushort* __restrict__ xcol,
    ushort* __restrict__ kTb, ushort* __restrict__ vTtb)
{
    __shared__ __align__(16) ushort lds[16384];
    ushort* Ws = lds; ushort* Xs = lds + 8192;
    const int tid = threadIdx.x, lane = tid & 63, w = tid >> 6;
    const int g = lane >> 4, i16 = lane & 15;
    const int pp0 = blockIdx.x * 128, m0 = blockIdx.y * 128, bb = blockIdx.z;
    const int wm = (w >> 1) * 64, wp = (w & 1) * 64;
    const ushort* Ag = Wkvbb + (size_t)m0 * 1024;
    const ushort* Bg = xcol + ((size_t)bb * 1024 + pp0) * 1024;
    f32x4 acc[4][4] = {};
    for (int ks = 0; ks < 16; ++ks) {
        stage_tile(Ag, 1024, ks * 64, Ws, w, lane);
        stage_tile(Bg, 1024, ks * 64, Xs, w, lane);
        __syncthreads();
        MFMA_STEP(Ws, Xs, wm, wp);
        __syncthreads();
    }
    if (m0 < 256) {
        #pragma unroll
        for (int fp = 0; fp < 4; ++fp) {
            const int pp = pp0 + wp + fp * 16 + i16;
            #pragma unroll
            for (int fm = 0; fm < 4; ++fm) {
                const int m = m0 + wm + fm * 16 + 4 * g;
                ushort4 v;
                v.x = f2bf(acc[fm][fp][0]); v.y = f2bf(acc[fm][fp][1]);
                v.z = f2bf(acc[fm][fp][2]); v.w = f2bf(acc[fm][fp][3]);
                *(ushort4*)&kTb[((size_t)bb * 1024 + pp) * 256 + m] = v;
            }
        }
    } else {
        // transpose 128(m) x 128(pp) through LDS, then coalesced rows out
        ushort (*T)[128] = (ushort(*)[128])lds;
        #pragma unroll
        for (int fm = 0; fm < 4; ++fm)
            #pragma unroll
            for (int fp = 0; fp < 4; ++fp)
                #pragma unroll
                for (int r = 0; r < 4; ++r)
                    T[wm + fm * 16 + 4 * g + r][wp + fp * 16 + i16] = f2bf(acc[fm][fp][r]);
        __syncthreads();
        #pragma unroll
        for (int u = 0; u < 8; ++u) {
            const int chunk = u * 256 + tid;
            const int row = chunk >> 4, slot = chunk & 15;
            const int mg = m0 - 256 + row;
            const int hh = mg >> 5, cc = mg & 31;
            const uint4 val = *(uint4*)&T[row][slot * 8];
            *(uint4*)&vTtb[((size_t)(bb * 8 + hh) * 32 + cc) * 1024 + pp0 + slot * 8] = val;
        }
    }
}

// ---------------------------------------------------------------------------
// out_mfma: out[b][o][p] = sum_c Wout[o][c]*sumT[b][p][c]. A=S(p rows), B=W.
// ---------------------------------------------------------------------------
__global__ __launch_bounds__(256) void out_mfma(
    const float* __restrict__ sumT, const ushort* __restrict__ Woutb,
    float* __restrict__ out)
{
    __shared__ __align__(16) ushort lds[16384];
    ushort* Ss = lds; ushort* Wo = lds + 8192;
    const int tid = threadIdx.x, lane = tid & 63, w = tid >> 6;
    const int g = lane >> 4, i16 = lane & 15;
    const int p0 = blockIdx.x * 128, o0 = blockIdx.y * 128, bb = blockIdx.z;
    const int wpp = (w >> 1) * 64, wo = (w & 1) * 64;
    const float* Sg = sumT + ((size_t)bb * 4096 + p0) * 256;
    const ushort* Bgw = Woutb + (size_t)o0 * 256;
    const int srow = tid >> 1, shalf = tid & 1;
    f32x4 acc[4][4] = {};
    for (int ks = 0; ks < 4; ++ks) {
        {   // reg-stage A: fp32 -> bf16, swizzled ds_write
            const float* src = Sg + (size_t)srow * 256 + ks * 64 + shalf * 32;
            #pragma unroll
            for (int jj = 0; jj < 4; ++jj) {
                const float4 f0 = *(const float4*)&src[jj * 8];
                const float4 f1 = *(const float4*)&src[jj * 8 + 4];
                uint4 pk;
                pk.x = pk2(f0.x, f0.y); pk.y = pk2(f0.z, f0.w);
                pk.z = pk2(f1.x, f1.y); pk.w = pk2(f1.z, f1.w);
                const int slog = shalf * 4 + jj;
                const int sp = slog ^ (srow & 7);
                *(uint4*)&Ss[(size_t)srow * 64 + sp * 8] = pk;
            }
        }
        stage_tile(Bgw, 256, ks * 64, Wo, w, lane);
        __syncthreads();
        MFMA_STEP(Ss, Wo, wpp, wo);
        __syncthreads();
    }
    #pragma unroll
    for (int fo = 0; fo < 4; ++fo) {
        const int o = o0 + wo + fo * 16 + i16;
        #pragma unroll
        for (int fp = 0; fp < 4; ++fp) {
            const int p = p0 + wpp + fp * 16 + 4 * g;
            const float4 v = make_float4(acc[fp][fo][0], acc[fp][fo][1],
                                         acc[fp][fo][2], acc[fp][fo][3]);
            *(float4*)&out[(size_t)bb * 1048576 + (size_t)o * 4096 + p] = v;
        }
    }
}

// ---------------------------------------------------------------------------
// attn_img_mfma: 32x32 swapped MFMA flash attention.
// Per block: one (b,h), 4 waves x 32 q-rows. KV staged in LDS, 128/tile.
// QK^T: S = mfma32(K,Q): lane column = q-row; 64 scores/lane per tile
// (hi-half split). Softmax stats lane-local + 1 permlane32_swap.
// PV: O^T = mfma32(V^T, P^T); P->B-frag via cvt_pk + permlane32_swap (T12).
// ---------------------------------------------------------------------------
__global__ __launch_bounds__(256) void attn_img_mfma(
    const ushort* __restrict__ qTb, const ushort* __restrict__ kTb,
    const ushort* __restrict__ vTtb, float* __restrict__ sumT)
{
    __shared__ ushort Ks[128][40];    // [kpos][32ch + pad8]
    __shared__ ushort Vts[32][136];   // [ch][128pos + pad8]
    const int tid  = threadIdx.x;
    const int lane = tid & 63;
    const int wv   = tid >> 6;
    const int q    = lane & 31;       // this lane's q-row (C/D column)
    const int hi   = lane >> 5;
    const int bh   = blockIdx.x;
    const int b    = bh >> 3, h = bh & 7;
    const int q0   = blockIdx.y * 128 + wv * 32;

    // Q B-frags: lane holds Q[q0+q][h*32 + mm*16 + 8*hi + jj]
    bf16x8 qf[2];
    #pragma unroll
    for (int mm = 0; mm < 2; ++mm)
        qf[mm] = *(const bf16x8*)(qTb + ((size_t)(b * 4096 + q0 + q) * 256 + h * 32 + mm * 16 + hi * 8));

    f32x16 o = {};                    // O^T[c][q]: col=q, c=(r&3)+8*(r>>2)+4*hi
    float mrun = -3.0e38f, lrun = 0.f;

    const ushort* kg = kTb + (size_t)b * 1024 * 256 + h * 32;
    const ushort* vg = vTtb + (size_t)bh * 32 * 1024;

    for (int kv0 = 0; kv0 < 1024; kv0 += 128) {
        __syncthreads();
        #pragma unroll
        for (int u = 0; u < 2; ++u) {
            const int chunk = tid + u * 256;
            const int r = chunk >> 2, q4 = chunk & 3;
            *(uint4*)&Ks[r][q4 * 8] = *(const uint4*)(kg + (size_t)(kv0 + r) * 256 + q4 * 8);
            const int c = chunk >> 4, sseg = chunk & 15;
            *(uint4*)&Vts[c][sseg * 8] = *(const uint4*)(vg + (size_t)c * 1024 + kv0 + sseg * 8);
        }
        __syncthreads();

        // ---- QK^T: 4 subtiles of 32 kpos; S[kpos][q] ----
        f32x16 s[4];
        #pragma unroll
        for (int t = 0; t < 4; ++t) {
            const bf16x8 k0 = *(const bf16x8*)&Ks[t * 32 + q][hi * 8];
            const bf16x8 k1 = *(const bf16x8*)&Ks[t * 32 + q][16 + hi * 8];
            f32x16 acc = {};
            acc = __builtin_amdgcn_mfma_f32_32x32x16_bf16(k0, qf[0], acc, 0, 0, 0);
            acc = __builtin_amdgcn_mfma_f32_32x32x16_bf16(k1, qf[1], acc, 0, 0, 0);
            s[t] = acc;
        }
        // ---- online softmax: lane-local + one cross-half swap ----
        float pmax = -3.0e38f;
        #pragma unroll
        for (int t = 0; t < 4; ++t)
            #pragma unroll
            for (int r = 0; r < 16; ++r) pmax = fmaxf(pmax, s[t][r]);
        {
            float a_ = pmax, b_ = pmax;
            asm volatile("v_permlane32_swap_b32 %0, %1" : "+v"(a_), "+v"(b_));
            pmax = fmaxf(a_, b_);
        }
        const float mnew  = fmaxf(mrun, pmax);
        const float alpha = __expf(mrun - mnew);
        mrun = mnew;
        float ls = 0.f;
        #pragma unroll
        for (int t = 0; t < 4; ++t)
            #pragma unroll
            for (int r = 0; r < 16; ++r) {
                const float p = __expf(s[t][r] - mnew);
                s[t][r] = p; ls += p;
            }
        {
            float a_ = ls, b_ = ls;
            asm volatile("v_permlane32_swap_b32 %0, %1" : "+v"(a_), "+v"(b_));
            ls = a_ + b_;
        }
        lrun = lrun * alpha + ls;
        #pragma unroll
        for (int r = 0; r < 16; ++r) o[r] *= alpha;

        // ---- PV: per subtile, pack P -> swap halves -> 2 mfma ----
        #pragma unroll
        for (int t = 0; t < 4; ++t) {
            unsigned int W[4][2];     // W[u][v]: bf16 pair at j = 8u+4hi+2v
            #pragma unroll
            for (int u = 0; u < 4; ++u) {
                asm("v_cvt_pk_bf16_f32 %0, %1, %2"
                    : "=v"(W[u][0]) : "v"(s[t][4 * u + 0]), "v"(s[t][4 * u + 1]));
                asm("v_cvt_pk_bf16_f32 %0, %1, %2"
                    : "=v"(W[u][1]) : "v"(s[t][4 * u + 2]), "v"(s[t][4 * u + 3]));
            }
            #pragma unroll
            for (int mm = 0; mm < 2; ++mm) {
                unsigned int a0 = W[2 * mm][0], b0 = W[2 * mm + 1][0];
                unsigned int a1 = W[2 * mm][1], b1 = W[2 * mm + 1][1];
                asm volatile("v_permlane32_swap_b32 %0, %1" : "+v"(a0), "+v"(b0));
                asm volatile("v_permlane32_swap_b32 %0, %1" : "+v"(a1), "+v"(b1));
                unsigned int pw[4] = {a0, a1, b0, b1};   // words jj 01,23,45,67
                const bf16x8 pf = *(const bf16x8*)pw;
                const bf16x8 vf = *(const bf16x8*)&Vts[q][t * 32 + mm * 16 + hi * 8];
                o = __builtin_amdgcn_mfma_f32_32x32x16_bf16(vf, pf, o, 0, 0, 0);
            }
        }
    }

    // ---- epilogue: all lane-local ----
    const float inv = 1.f / lrun;
    float* dst = sumT + (size_t)(b * 4096 + q0 + q) * 256 + h * 32 + hi * 4;
    #pragma unroll
    for (int u = 0; u < 4; ++u) {
        const float4 v = make_float4(o[4 * u + 0] * inv, o[4 * u + 1] * inv,
                                     o[4 * u + 2] * inv, o[4 * u + 3] * inv);
        *(float4*)&dst[u * 8] = v;   // c = 8u + 4hi + {0..3}
    }
}

// ---------------------------------------------------------------------------
// attn_batch: unchanged
// ---------------------------------------------------------------------------
__global__ __launch_bounds__(256) void attn_batch_kernel(
    const float* __restrict__ qbT, const ushort* __restrict__ kvbT,
    float* __restrict__ sumT)
{
    const int tid = threadIdx.x;
    const int b1 = tid & 3, h = (tid >> 2) & 7, pl = tid >> 5;
    const int p = blockIdx.x * 8 + pl;

    const float* qrow = qbT + ((size_t)b1 * 4096 + p) * 256 + h * 32;
    float q[32];
    #pragma unroll
    for (int i = 0; i < 8; ++i) {
        const float4 t = ((const float4*)qrow)[i];
        q[4 * i + 0] = t.x * ATTN_SCALE; q[4 * i + 1] = t.y * ATTN_SCALE;
        q[4 * i + 2] = t.z * ATTN_SCALE; q[4 * i + 3] = t.w * ATTN_SCALE;
    }

    float s[4];
    #pragma unroll
    for (int b2 = 0; b2 < 4; ++b2) {
        const uint4* k4 = (const uint4*)(kvbT + ((size_t)b2 * 4096 + p) * 512 + h * 32);
        float d = 0.f;
        #pragma unroll
        for (int i = 0; i < 4; ++i) {
            const uint4 w = k4[i];
            d += q[8 * i + 0] * bf2f(w.x & 0xffffu) + q[8 * i + 1] * bf2f(w.x >> 16);
            d += q[8 * i + 2] * bf2f(w.y & 0xffffu) + q[8 * i + 3] * bf2f(w.y >> 16);
            d += q[8 * i + 4] * bf2f(w.z & 0xffffu) + q[8 * i + 5] * bf2f(w.z >> 16);
            d += q[8 * i + 6] * bf2f(w.w & 0xffffu) + q[8 * i + 7] * bf2f(w.w >> 16);
        }
        s[b2] = d;
    }
    const float mx = fmaxf(fmaxf(s[0], s[1]), fmaxf(s[2], s[3]));
    float w[4];
    float lsum = 0.f;
    #pragma unroll
    for (int b2 = 0; b2 < 4; ++b2) { w[b2] = __expf(s[b2] - mx); lsum += w[b2]; }
    const float inv = 1.f / lsum;
    #pragma unroll
    for (int b2 = 0; b2 < 4; ++b2) w[b2] *= inv;

    float acc[32] = {};
    #pragma unroll
    for (int b2 = 0; b2 < 4; ++b2) {
        const uint4* v4 = (const uint4*)(kvbT + ((size_t)b2 * 4096 + p) * 512 + 256 + h * 32);
        const float wb = w[b2];
        #pragma unroll
        for (int i = 0; i < 4; ++i) {
            const uint4 vv = v4[i];
            acc[8 * i + 0] += wb * bf2f(vv.x & 0xffffu); acc[8 * i + 1] += wb * bf2f(vv.x >> 16);
            acc[8 * i + 2] += wb * bf2f(vv.y & 0xffffu); acc[8 * i + 3] += wb * bf2f(vv.y >> 16);
            acc[8 * i + 4] += wb * bf2f(vv.z & 0xffffu); acc[8 * i + 5] += wb * bf2f(vv.z >> 16);
            acc[8 * i + 6] += wb * bf2f(vv.w & 0xffffu); acc[8 * i + 7] += wb * bf2f(vv.w >> 16);
        }
    }
    float4* o4 = (float4*)(sumT + ((size_t)b1 * 4096 + p) * 256 + h * 32);
    #pragma unroll
    for (int i = 0; i < 8; ++i) {
        float4 c = o4[i];
        c.x += acc[4 * i + 0]; c.y += acc[4 * i + 1];
        c.z += acc[4 * i + 2]; c.w += acc[4 * i + 3];
        o4[i] = c;
    }
}

// ---------------------------------------------------------------------------
extern "C" void kernel_launch(void* const* d_in, const int* in_sizes, int n_in,
                              void* d_out, int out_size, void* d_ws, size_t ws_size,
                              hipStream_t stream)
{
    const float* x    = (const float*)d_in[0];
    const float* Wq   = (const float*)d_in[1];
    const float* Wkv  = (const float*)d_in[2];
    const float* Wqb  = (const float*)d_in[3];
    const float* Wkvb = (const float*)d_in[4];
    const float* Wout = (const float*)d_in[5];
    float* out = (float*)d_out;

    // workspace (ushort units). sumT (fp32, 16.78MB) aliases xbfT+xcol, which
    // are dead before attn_img writes sumT. Total: 47.8 MB.
    ushort* base  = (ushort*)d_ws;
    ushort* xbfT  = base;                    // 4,194,304
    ushort* xcol  = base + 4194304;          // 4,194,304
    ushort* Wallb = base + 8388608;          //   262,144
    ushort* Wkvbb = base + 8650752;          //   524,288
    float*  sumT  = (float*)base;            // aliases [0, 8388608) ushorts
    ushort* qTb   = base + 9175040;          // 4,194,304
    ushort* kvbT  = base + 13369344;         // 8,388,608
    ushort* kTb   = base + 21757952;         // 1,048,576
    ushort* vTtb  = base + 22806528;         // 1,048,576
    ushort* Woutb = base + 23855104;         //    65,536
    float* qbT = out;                        // d_out reused as qb scratch

    cvt_x_kernel<<<dim3(64, 4, 4), 256, 0, stream>>>(x, xbfT);
    cvt_w_kernel<<<dim3(832), 256, 0, stream>>>(Wq, Wqb, Wkvb, Wkv, Wout, Wallb, Wkvbb, Woutb);
    cvt_xcol_kernel<<<dim3(256, 4), 256, 0, stream>>>(xbfT, xcol);
    proj_mfma<<<dim3(32, 8, 4), 256, 0, stream>>>(Wallb, xbfT, qTb, qbT, kvbT);
    conv_mfma<<<dim3(8, 4, 4), 256, 0, stream>>>(Wkvbb, xcol, kTb, vTtb);
    attn_img_mfma<<<dim3(32, 32), 256, 0, stream>>>(qTb, kTb, vTtb, sumT);
    attn_batch_kernel<<<dim3(512), 256, 0, stream>>>(qbT, kvbT, sumT);
    out_mfma<<<dim3(32, 2, 4), 256, 0, stream>>>(sumT, Woutb, out);
}